// Round 6
// baseline (308.744 us; speedup 1.0000x reference)
//
#include <hip/hip_runtime.h>
#include <cstdint>

#define B_    128
#define T_    2048
#define NIN_  16
#define NH_   128
#define NOUT_ 5

#define ALPHA_I_ 0.75f
#define ALPHA_V_ 0.96875f
#define THETA_   64.0f

#define NCHUNK_ 8
#define CHT_    256     // data timesteps per chunk
#define WARM_   96      // warmup timesteps (3 sub-chunks of 32)

typedef short bf16x8 __attribute__((ext_vector_type(8)));
typedef float f32x16 __attribute__((ext_vector_type(16)));

__device__ __forceinline__ float mulrn(float a, float b) { return __fmul_rn(a, b); }
__device__ __forceinline__ float addrn(float a, float b) { return __fadd_rn(a, b); }

__device__ __forceinline__ uint16_t f2bf(float x) {  // RNE f32->bf16
  uint32_t u = __float_as_uint(x);
  return (uint16_t)((u + 0x7FFFu + ((u >> 16) & 1u)) >> 16);
}

// nibble LUT (16 x uint2 in LDS, bank-conflict-free): bit j -> bf16 1.0/0.0
__device__ __forceinline__ bf16x8 expand8(const uint2* __restrict__ lut, uint32_t byt) {
  uint2 lo = lut[byt & 15u];
  uint2 h  = lut[byt >> 4];
  union { uint32_t w[4]; bf16x8 f; } r;
  r.w[0] = lo.x; r.w[1] = lo.y; r.w[2] = h.x; r.w[3] = h.y;
  return r.f;
}

// ---------------------------------------------------------------------------
// prep (1024 threads): weight_norm (x64 folded). w1swz: layer-1 weights bf16
// in 32x32x16 B-fragment order per o-tile. wswz: layer-2 Wf=w*f / Wof=w*(1-f)
// (axon-delay-1 interp folded), B-fragment order (same index formula as the
// R4/R5-verified swizzle). w3T[c][0..4]=w3, [5]=f2,[6]=1-f2. efo: e=floor(d)+1.
// ---------------------------------------------------------------------------
__global__ __launch_bounds__(1024) void prep_kernel(
    const float* __restrict__ fc1_v, const float* __restrict__ fc1_g,
    const float* __restrict__ fc2_v, const float* __restrict__ fc2_g,
    const float* __restrict__ fc3_v, const float* __restrict__ fc3_g,
    const float* __restrict__ delay1, const float* __restrict__ delay2,
    uint16_t* __restrict__ w1swz, uint16_t* __restrict__ wswz,
    float* __restrict__ w3T, float4* __restrict__ efo1, float4* __restrict__ efo2,
    float* __restrict__ counts) {
  __shared__ float s_g2[NH_], s_n2[NH_];
  int tid = threadIdx.x;
  if (tid < NH_) {
    // fc2 row norms (for phase 2)
    {
      float ss = 0.f;
      for (int c = 0; c < NH_; c++) { float vv = fc2_v[tid * NH_ + c]; ss = __fmaf_rn(vv, vv, ss); }
      s_n2[tid] = sqrtf(ss);
      s_g2[tid] = fc2_g[tid];
    }
    // layer 1 row -> B-fragment swizzle
    {
      float ss = 0.f;
      for (int c = 0; c < NIN_; c++) { float vv = fc1_v[tid * NIN_ + c]; ss = __fmaf_rn(vv, vv, ss); }
      float nrm = sqrtf(ss);
      float g = fc1_g[tid];
      int mt = tid >> 5;
      for (int c = 0; c < NIN_; c++) {
        float wv = 64.0f * __fdiv_rn(mulrn(g, fc1_v[tid * NIN_ + c]), nrm);
        int lane = (tid & 31) + 32 * ((c >> 3) & 1);
        int j = c & 7;
        w1swz[(mt * 64 + lane) * 8 + j] = f2bf(wv);
      }
    }
    // delay tables
    {
      float d1 = delay1[tid];
      float fl = floorf(d1);
      float f = __fsub_rn(d1, fl);
      efo1[tid] = make_float4(__int_as_float((int)fl + 1), f, __fsub_rn(1.0f, f), 0.f);
      float d2 = delay2[tid];
      float fl2 = floorf(d2);
      float f2v = __fsub_rn(d2, fl2);
      efo2[tid] = make_float4(__int_as_float((int)fl2 + 1), f2v, __fsub_rn(1.0f, f2v), 0.f);
      w3T[tid * 8 + 5] = f2v;
      w3T[tid * 8 + 6] = __fsub_rn(1.0f, f2v);
      w3T[tid * 8 + 7] = 0.f;
    }
  }
  if (tid < NOUT_) {
    float ss = 0.f;
    for (int c = 0; c < NH_; c++) { float vv = fc3_v[tid * NH_ + c]; ss = __fmaf_rn(vv, vv, ss); }
    float nrm = sqrtf(ss);
    float g = fc3_g[tid];
    for (int c = 0; c < NH_; c++)
      w3T[c * 8 + tid] = 64.0f * __fdiv_rn(mulrn(g, fc3_v[tid * NH_ + c]), nrm);
  }
  if (tid < 3) counts[tid] = 0.f;
  __syncthreads();
  // phase 2: layer-2 swizzle, all 1024 threads (c-major -> coalesced reads)
  for (int i = tid; i < NH_ * NH_; i += 1024) {
    int o = i >> 7, c = i & 127;
    float wv = 64.0f * __fdiv_rn(mulrn(s_g2[o], fc2_v[i]), s_n2[o]);
    float d1 = delay1[c];
    float f = __fsub_rn(d1, floorf(d1));
    int lane = (o & 31) + 32 * ((c >> 3) & 1);
    int ks = c >> 4, j = c & 7, mt = o >> 5;
    wswz[((size_t)((0 * 4 + mt) * 8 + ks) * 64 + lane) * 8 + j] = f2bf(__fmul_rn(wv, f));
    wswz[((size_t)((1 * 4 + mt) * 8 + ks) * 64 + lane) * 8 + j] =
        f2bf(__fmul_rn(wv, __fsub_rn(1.0f, f)));
  }
}

// ---------------------------------------------------------------------------
// pack: input f32 spikes (B,16,T) -> 16-bit channel masks Xb[b][t] via ballot.
// ---------------------------------------------------------------------------
__global__ __launch_bounds__(256) void pack_kernel(const float* __restrict__ spike,
                                                   uint16_t* __restrict__ Xb) {
  int gw = blockIdx.x * 4 + (threadIdx.x >> 6);
  int lane = threadIdx.x & 63;
  int b = gw >> 5;
  int t = (gw & 31) * 64 + lane;
  const float* sp = spike + (size_t)b * NIN_ * T_ + t;
  uint32_t mask = 0;
#pragma unroll
  for (int c = 0; c < NIN_; c++) {
    unsigned long long bal = __ballot(sp[(size_t)c * T_] != 0.f);
    mask |= (uint32_t)((bal >> lane) & 1ull) << c;
  }
  Xb[(size_t)b * T_ + t] = (uint16_t)mask;
}

// ---------------------------------------------------------------------------
// In-register Loihi scan over a wave's 32t x 32o register tile (D-layout:
// o = lane&31, t-row = (r&3)+8*(r>>2)+4*hi). Quad q of 4 t's lives in half
// (q&1), regs 4*(q>>1)..+3. State (u,v) hops halves via shfl_xor(32).
// Returns bit mask m (valid bits only in own half's quads).
// ---------------------------------------------------------------------------
#define SCAN_TILE(acc, u, v, m)                                        \
  {                                                                    \
    m = 0u;                                                            \
    _Pragma("unroll") for (int q = 0; q < 8; q++) {                    \
      u = __shfl_xor(u, 32, 64);                                       \
      v = __shfl_xor(v, 32, 64);                                       \
      _Pragma("unroll") for (int j = 0; j < 4; j++) {                  \
        float z = acc[4 * (q >> 1) + j];                               \
        u = addrn(mulrn(ALPHA_I_, u), z);                              \
        v = addrn(mulrn(ALPHA_V_, v), u);                              \
        bool sbit = (v >= THETA_);                                     \
        v = sbit ? 0.f : v;                                            \
        m |= sbit ? (1u << (4 * q + j)) : 0u;                          \
      }                                                                \
    }                                                                  \
  }

// ---------------------------------------------------------------------------
// Fused layer 1: A=input spike bits (m=t), B=weights (n=o), 1 MFMA/group,
// in-register scan, bitpacked output + counts. No barriers in the loop.
// grid (NCHUNK_, B), block 256 (4 waves = 4 o-tiles).
// ---------------------------------------------------------------------------
__global__ __launch_bounds__(256) void fused_layer1(const uint16_t* __restrict__ Xb,
                                                    const uint16_t* __restrict__ w1swz,
                                                    uint32_t* __restrict__ sbits2,
                                                    float* __restrict__ cnt) {
  __shared__ uint2 s_lut[16];
  int tid = threadIdx.x;
  int wv = tid >> 6, lane = tid & 63;
  int hi = lane >> 5, tl = lane & 31;
  int ci = blockIdx.x, b = blockIdx.y;
  if (tid < 16) {
    uint32_t w0 = ((tid & 1) ? 0x3F80u : 0u) | ((tid & 2) ? 0x3F800000u : 0u);
    uint32_t w1 = ((tid & 4) ? 0x3F80u : 0u) | ((tid & 8) ? 0x3F800000u : 0u);
    s_lut[tid] = make_uint2(w0, w1);
  }
  bf16x8 wfrag = ((const bf16x8*)w1swz)[wv * 64 + lane];
  __syncthreads();

  int wch = (ci == 0) ? 0 : (WARM_ / 32);
  int nch = CHT_ / 32 + wch;
  int chbase0 = ci * CHT_ - wch * 32;
  const uint16_t* xb = Xb + (size_t)b * T_;
  uint32_t* sb = sbits2 + (size_t)b * 68 * NH_;
  uint32_t mymask = hi ? 0xF0F0F0F0u : 0x0F0F0F0Fu;

  float u = 0.f, v = 0.f, csum = 0.f;
  uint32_t x = xb[chbase0 + tl];
  for (int g = 0; g < nch; g++) {
    uint32_t xn = (g + 1 < nch) ? (uint32_t)xb[chbase0 + (g + 1) * 32 + tl] : 0u;
    uint32_t byt = (x >> (8 * hi)) & 0xFFu;
    bf16x8 afr = expand8(s_lut, byt);
    f32x16 acc;
#pragma unroll
    for (int r = 0; r < 16; r++) acc[r] = 0.f;
    acc = __builtin_amdgcn_mfma_f32_32x32x16_bf16(afr, wfrag, acc, 0, 0, 0);
    uint32_t m;
    SCAN_TILE(acc, u, v, m);
    uint32_t mfull = (m & mymask) | (__shfl_xor(m, 32, 64) & ~mymask);
    if (g >= wch && lane < 32) {
      int gw = (chbase0 + g * 32) >> 5;
      sb[(2 + gw) * NH_ + wv * 32 + lane] = mfull;
      int pc = __popc(mfull);
      if (gw == 63) pc -= (int)(mfull >> 31);
      csum += (float)pc;
    }
    x = xn;
  }
  if (ci == 0 && lane < 32) {
    sb[0 * NH_ + wv * 32 + lane] = 0u;
    sb[1 * NH_ + wv * 32 + lane] = 0u;
  }
  if (ci == NCHUNK_ - 1 && lane < 32) {
    sb[66 * NH_ + wv * 32 + lane] = 0u;
    sb[67 * NH_ + wv * 32 + lane] = 0u;
  }
  for (int off = 32; off; off >>= 1) csum += __shfl_down(csum, off, 64);
  if (lane == 0) atomicAdd(cnt, csum);
}

// ---------------------------------------------------------------------------
// Fused layer 2: A=delay-pre-shifted spike bits (2 taps), B=Wf/Wof fragments
// in regs, 16 MFMA/group, in-register scan. No barriers in the loop.
// ---------------------------------------------------------------------------
__global__ __launch_bounds__(256) void fused_layer2(const uint32_t* __restrict__ PTpad,
                                                    const uint16_t* __restrict__ wswz,
                                                    uint32_t* __restrict__ sbits2,
                                                    float* __restrict__ cnt) {
  __shared__ uint2 s_lut[16];
  int tid = threadIdx.x;
  int wv = tid >> 6, lane = tid & 63;
  int hi = lane >> 5, tl = lane & 31;
  int ci = blockIdx.x, b = blockIdx.y;
  if (tid < 16) {
    uint32_t w0 = ((tid & 1) ? 0x3F80u : 0u) | ((tid & 2) ? 0x3F800000u : 0u);
    uint32_t w1 = ((tid & 4) ? 0x3F80u : 0u) | ((tid & 8) ? 0x3F800000u : 0u);
    s_lut[tid] = make_uint2(w0, w1);
  }
  const bf16x8* wsv = (const bf16x8*)wswz;
  bf16x8 wf[8], wo[8];
#pragma unroll
  for (int ks = 0; ks < 8; ks++) {
    wf[ks] = wsv[((size_t)((0 * 4 + wv) * 8 + ks) * 64) + lane];
    wo[ks] = wsv[((size_t)((1 * 4 + wv) * 8 + ks) * 64) + lane];
  }
  __syncthreads();

  int wch = (ci == 0) ? 0 : (WARM_ / 32);
  int nch = CHT_ / 32 + wch;
  int chbase0 = ci * CHT_ - wch * 32;
  const uint4* pt = (const uint4*)PTpad + (size_t)b * (T_ + 1);
  uint32_t* sb = sbits2 + (size_t)b * 68 * NH_;
  uint32_t mymask = hi ? 0xF0F0F0F0u : 0x0F0F0F0Fu;

  float u = 0.f, v = 0.f, csum = 0.f;
  uint4 R0 = pt[chbase0 + tl];
  uint4 R1 = pt[chbase0 + tl + 1];
  for (int g = 0; g < nch; g++) {
    uint4 R0n = R0, R1n = R1;
    if (g + 1 < nch) {
      R0n = pt[chbase0 + (g + 1) * 32 + tl];
      R1n = pt[chbase0 + (g + 1) * 32 + tl + 1];
    }
    uint32_t r0w[4] = {R0.x, R0.y, R0.z, R0.w};
    uint32_t r1w[4] = {R1.x, R1.y, R1.z, R1.w};
    f32x16 acc;
#pragma unroll
    for (int r = 0; r < 16; r++) acc[r] = 0.f;
#pragma unroll
    for (int ks = 0; ks < 8; ks++) {
      int sh = 16 * (ks & 1) + 8 * hi;
      uint32_t b0 = (r0w[ks >> 1] >> sh) & 0xFFu;  // tap s[t-e-1] -> Wf
      uint32_t b1 = (r1w[ks >> 1] >> sh) & 0xFFu;  // tap s[t-e]   -> Wof
      acc = __builtin_amdgcn_mfma_f32_32x32x16_bf16(expand8(s_lut, b0), wf[ks], acc, 0, 0, 0);
      acc = __builtin_amdgcn_mfma_f32_32x32x16_bf16(expand8(s_lut, b1), wo[ks], acc, 0, 0, 0);
    }
    uint32_t m;
    SCAN_TILE(acc, u, v, m);
    uint32_t mfull = (m & mymask) | (__shfl_xor(m, 32, 64) & ~mymask);
    if (g >= wch && lane < 32) {
      int gw = (chbase0 + g * 32) >> 5;
      sb[(2 + gw) * NH_ + wv * 32 + lane] = mfull;
      int pc = __popc(mfull);
      if (gw == 63) pc -= (int)(mfull >> 31);
      csum += (float)pc;
    }
    R0 = R0n; R1 = R1n;
  }
  if (ci == 0 && lane < 32) {
    sb[0 * NH_ + wv * 32 + lane] = 0u;
    sb[1 * NH_ + wv * 32 + lane] = 0u;
  }
  if (ci == NCHUNK_ - 1 && lane < 32) {
    sb[66 * NH_ + wv * 32 + lane] = 0u;
    sb[67 * NH_ + wv * 32 + lane] = 0u;
  }
  for (int off = 32; off; off >>= 1) csum += __shfl_down(csum, off, 64);
  if (lane == 0) atomicAdd(cnt, csum);
}

// ---------------------------------------------------------------------------
// bit transpose + delay pre-shift: PTpad[b][1+t] row (128 bits) bit c =
// s[c][t - e_c]; PTpad[b][0] = 0. Reads sbits2[b][slot][o] layout.
// ---------------------------------------------------------------------------
__global__ __launch_bounds__(256) void transpose_kernel(const uint32_t* __restrict__ sbits2,
                                                        const float4* __restrict__ efo,
                                                        uint32_t* __restrict__ PTpad) {
  __shared__ uint32_t rows[NH_ * 69];
  int tid = threadIdx.x;
  int b = blockIdx.x;
  const uint32_t* src = sbits2 + (size_t)b * 68 * NH_;
  for (int i = tid; i < 68 * NH_; i += 256) {
    int w = i >> 7, c = i & 127;
    rows[c * 69 + w] = src[i];
  }
  __syncthreads();

  uint4* outp = (uint4*)PTpad + (size_t)b * (T_ + 1);
  if (tid == 0) outp[0] = make_uint4(0u, 0u, 0u, 0u);

  int t0 = tid * 8;
  uint32_t wacc[8][4];
#pragma unroll
  for (int i = 0; i < 8; i++)
#pragma unroll
    for (int j = 0; j < 4; j++) wacc[i][j] = 0u;

#pragma unroll
  for (int c = 0; c < NH_; c++) {
    int e = __float_as_int(efo[c].x);
    int bitpos0 = t0 - e;
    int wi = bitpos0 >> 5;
    int sh = bitpos0 & 31;
    uint32_t lo = rows[c * 69 + 2 + wi];
    uint32_t hi2 = rows[c * 69 + 3 + wi];
    uint32_t bits8 = (uint32_t)(((((unsigned long long)hi2 << 32) | lo) >> sh)) & 0xFFu;
#pragma unroll
    for (int i = 0; i < 8; i++)
      wacc[i][c >> 5] |= ((bits8 >> i) & 1u) << (c & 31);
  }

#pragma unroll
  for (int i = 0; i < 8; i++)
    outp[1 + t0 + i] = make_uint4(wacc[i][0], wacc[i][1], wacc[i][2], wacc[i][3]);
}

// ---------------------------------------------------------------------------
// gemm3 (vector): 5 outputs from pre-shifted PT rows.
// ---------------------------------------------------------------------------
__global__ __launch_bounds__(256) void gemm3_kernel(const uint32_t* __restrict__ PTpad,
                                                    const float* __restrict__ w3T,
                                                    float* __restrict__ z) {
  int tid = threadIdx.x;
  int t = blockIdx.x * 256 + tid;
  int b = blockIdx.y;
  const uint4* pt = (const uint4*)PTpad + (size_t)b * (T_ + 1);
  uint4 R0 = pt[t];
  uint4 R1 = pt[t + 1];
  uint32_t r0w[4] = {R0.x, R0.y, R0.z, R0.w};
  uint32_t r1w[4] = {R1.x, R1.y, R1.z, R1.w};

  float acc[NOUT_];
#pragma unroll
  for (int o = 0; o < NOUT_; o++) acc[o] = 0.f;

#pragma unroll
  for (int c = 0; c < NH_; c++) {
    const float* wc = w3T + (c << 3);
    float f = wc[5], omf = wc[6];
    float fb0 = (float)((r0w[c >> 5] >> (c & 31)) & 1u);
    float fb1 = (float)((r1w[c >> 5] >> (c & 31)) & 1u);
    float val = __fmaf_rn(omf, fb1, __fmul_rn(f, fb0));
#pragma unroll
    for (int o = 0; o < NOUT_; o++) acc[o] = __fmaf_rn(wc[o], val, acc[o]);
  }

#pragma unroll
  for (int o = 0; o < NOUT_; o++)
    z[((size_t)b * NOUT_ + o) * T_ + t] = acc[o];
}

// ---------------------------------------------------------------------------
// Chunked layer-3 scan: thread per (chunk, b, o); 96-step warmup; f32 SHIFTED
// output (out[t]=s[t-1]) via float4 stores; count excludes t=T-1.
// ---------------------------------------------------------------------------
__global__ __launch_bounds__(256) void scan3_kernel(const float* __restrict__ z3,
                                                    float* __restrict__ out,
                                                    float* __restrict__ cnt) {
  int id = blockIdx.x * 256 + threadIdx.x;
  int row = id % (B_ * NOUT_);
  int ci = id / (B_ * NOUT_);
  int tstart = ci * CHT_;
  int t0 = (ci == 0) ? 0 : tstart - WARM_;
  const float4* zp4 = (const float4*)(z3 + (size_t)row * T_);

  float u = 0.f, v = 0.f, carry = 0.f;
  int cnt_i = 0;
  for (int gg = t0 / 16; gg < tstart / 16; gg++) {
#pragma unroll
    for (int q = 0; q < 4; q++) {
      float4 cv = zp4[gg * 4 + q];
      float zv[4] = {cv.x, cv.y, cv.z, cv.w};
#pragma unroll
      for (int j = 0; j < 4; j++) {
        u = addrn(mulrn(ALPHA_I_, u), zv[j]);
        v = addrn(mulrn(ALPHA_V_, v), u);
        bool s = (v >= THETA_);
        v = s ? 0.f : v;
        carry = s ? 1.f : 0.f;
      }
    }
  }
  float4* op4 = (float4*)(out + (size_t)row * T_ + tstart);
  for (int gg = 0; gg < CHT_ / 16; gg++) {
    float sarr[16];
#pragma unroll
    for (int q = 0; q < 4; q++) {
      float4 cv = zp4[(tstart / 16 + gg) * 4 + q];
      float zv[4] = {cv.x, cv.y, cv.z, cv.w};
#pragma unroll
      for (int j = 0; j < 4; j++) {
        u = addrn(mulrn(ALPHA_I_, u), zv[j]);
        v = addrn(mulrn(ALPHA_V_, v), u);
        bool s = (v >= THETA_);
        v = s ? 0.f : v;
        sarr[q * 4 + j] = s ? 1.f : 0.f;
      }
    }
#pragma unroll
    for (int k = 0; k < 16; k++) {
      int t = tstart + gg * 16 + k;
      if (t < T_ - 1) cnt_i += (sarr[k] != 0.f) ? 1 : 0;
    }
    op4[gg * 4 + 0] = make_float4(carry, sarr[0], sarr[1], sarr[2]);
    op4[gg * 4 + 1] = make_float4(sarr[3], sarr[4], sarr[5], sarr[6]);
    op4[gg * 4 + 2] = make_float4(sarr[7], sarr[8], sarr[9], sarr[10]);
    op4[gg * 4 + 3] = make_float4(sarr[11], sarr[12], sarr[13], sarr[14]);
    carry = sarr[15];
  }
  float c = (float)cnt_i;
  for (int off = 32; off; off >>= 1) c += __shfl_down(c, off, 64);
  if ((threadIdx.x & 63) == 0) atomicAdd(cnt, c);
}

// ---------------------------------------------------------------------------
extern "C" void kernel_launch(void* const* d_in, const int* in_sizes, int n_in,
                              void* d_out, int out_size, void* d_ws, size_t ws_size,
                              hipStream_t stream) {
  (void)in_sizes; (void)n_in; (void)out_size; (void)ws_size;
  const float* spike  = (const float*)d_in[0];
  const float* fc1_v  = (const float*)d_in[1];
  const float* fc1_g  = (const float*)d_in[2];
  const float* fc2_v  = (const float*)d_in[3];
  const float* fc2_g  = (const float*)d_in[4];
  const float* fc3_v  = (const float*)d_in[5];
  const float* fc3_g  = (const float*)d_in[6];
  const float* delay1 = (const float*)d_in[7];
  const float* delay2 = (const float*)d_in[8];
  float* out = (float*)d_out;

  float* ws = (float*)d_ws;
  float* w3T       = ws;                         // 1024 f
  float4* efo1     = (float4*)(ws + 1024);       // 512 f
  float4* efo2     = (float4*)(ws + 1536);       // 512 f
  uint16_t* w1swz  = (uint16_t*)(ws + 2048);     // 2048 u16 = 1024 f
  uint16_t* wswz   = (uint16_t*)(ws + 3072);     // 32768 u16 = 16384 f
  uint16_t* Xb     = (uint16_t*)(ws + 19456);    // B*T u16 = 131072 f
  uint32_t* sbits2 = (uint32_t*)(ws + 150528);   // B*68*128 u32
  uint32_t* PTpad  = (uint32_t*)(ws + 1264640);  // B*(T+1)*4 u32, 16B-aligned
  float* z3        = ws + 2313728;               // B*5*T f32
  float* counts = out + (size_t)B_ * NOUT_ * T_;

  prep_kernel<<<1, 1024, 0, stream>>>(fc1_v, fc1_g, fc2_v, fc2_g, fc3_v, fc3_g,
                                      delay1, delay2, w1swz, wswz, w3T, efo1, efo2, counts);

  pack_kernel<<<dim3(B_ * T_ / 64 / 4), 256, 0, stream>>>(spike, Xb);

  fused_layer1<<<dim3(NCHUNK_, B_), 256, 0, stream>>>(Xb, w1swz, sbits2, counts + 0);
  transpose_kernel<<<dim3(B_), 256, 0, stream>>>(sbits2, efo1, PTpad);

  fused_layer2<<<dim3(NCHUNK_, B_), 256, 0, stream>>>(PTpad, wswz, sbits2, counts + 1);
  transpose_kernel<<<dim3(B_), 256, 0, stream>>>(sbits2, efo2, PTpad);

  gemm3_kernel<<<dim3(T_ / 256, B_), 256, 0, stream>>>(PTpad, w3T, z3);
  scan3_kernel<<<dim3(NCHUNK_ * B_ * NOUT_ / 256), 256, 0, stream>>>(z3, out, counts + 2);
}

// Round 7
// 292.564 us; speedup vs baseline: 1.0553x; 1.0553x over previous
//
#include <hip/hip_runtime.h>
#include <cstdint>

#define B_    128
#define T_    2048
#define NIN_  16
#define NH_   128
#define NOUT_ 5

#define ALPHA_I_ 0.75f
#define ALPHA_V_ 0.96875f
#define THETA_   64.0f

#define NCHUNK_ 16
#define CHT_    128     // data timesteps per chunk
#define WARM_   96      // warmup timesteps (3 sub-chunks of 32)

typedef short bf16x8 __attribute__((ext_vector_type(8)));
typedef float f32x16 __attribute__((ext_vector_type(16)));

__device__ __forceinline__ float mulrn(float a, float b) { return __fmul_rn(a, b); }
__device__ __forceinline__ float addrn(float a, float b) { return __fadd_rn(a, b); }

__device__ __forceinline__ uint16_t f2bf(float x) {  // RNE f32->bf16
  uint32_t u = __float_as_uint(x);
  return (uint16_t)((u + 0x7FFFu + ((u >> 16) & 1u)) >> 16);
}

// nibble LUT (16 x uint2 in LDS, bank-conflict-free): bit j -> bf16 1.0/0.0
__device__ __forceinline__ bf16x8 expand8(const uint2* __restrict__ lut, uint32_t byt) {
  uint2 lo = lut[byt & 15u];
  uint2 h  = lut[byt >> 4];
  union { uint32_t w[4]; bf16x8 f; } r;
  r.w[0] = lo.x; r.w[1] = lo.y; r.w[2] = h.x; r.w[3] = h.y;
  return r.f;
}

__device__ __forceinline__ void lut_init(uint2* s_lut, int tid) {
  if (tid < 16) {
    uint32_t w0 = ((tid & 1) ? 0x3F80u : 0u) | ((tid & 2) ? 0x3F800000u : 0u);
    uint32_t w1 = ((tid & 4) ? 0x3F80u : 0u) | ((tid & 8) ? 0x3F800000u : 0u);
    s_lut[tid] = make_uint2(w0, w1);
  }
}

// ---------------------------------------------------------------------------
// prep (1024 threads): weight_norm (x64 folded). w1swz / wswz in the
// R5/R6-verified MFMA B-fragment swizzle. w3T[c][0..4]=w3, [5]=f2,[6]=1-f2.
// efo: e=floor(d)+1 (includes delay_shift1's +1). Zero counts.
// ---------------------------------------------------------------------------
__global__ __launch_bounds__(1024) void prep_kernel(
    const float* __restrict__ fc1_v, const float* __restrict__ fc1_g,
    const float* __restrict__ fc2_v, const float* __restrict__ fc2_g,
    const float* __restrict__ fc3_v, const float* __restrict__ fc3_g,
    const float* __restrict__ delay1, const float* __restrict__ delay2,
    uint16_t* __restrict__ w1swz, uint16_t* __restrict__ wswz,
    float* __restrict__ w3T, float4* __restrict__ efo1, float4* __restrict__ efo2,
    float* __restrict__ counts) {
  __shared__ float s_g2[NH_], s_n2[NH_];
  int tid = threadIdx.x;
  if (tid < NH_) {
    {
      float ss = 0.f;
      for (int c = 0; c < NH_; c++) { float vv = fc2_v[tid * NH_ + c]; ss = __fmaf_rn(vv, vv, ss); }
      s_n2[tid] = sqrtf(ss);
      s_g2[tid] = fc2_g[tid];
    }
    {
      float ss = 0.f;
      for (int c = 0; c < NIN_; c++) { float vv = fc1_v[tid * NIN_ + c]; ss = __fmaf_rn(vv, vv, ss); }
      float nrm = sqrtf(ss);
      float g = fc1_g[tid];
      int mt = tid >> 5;
      for (int c = 0; c < NIN_; c++) {
        float wv = 64.0f * __fdiv_rn(mulrn(g, fc1_v[tid * NIN_ + c]), nrm);
        int lane = (tid & 31) + 32 * ((c >> 3) & 1);
        int j = c & 7;
        w1swz[(mt * 64 + lane) * 8 + j] = f2bf(wv);
      }
    }
    {
      float d1 = delay1[tid];
      float fl = floorf(d1);
      float f = __fsub_rn(d1, fl);
      efo1[tid] = make_float4(__int_as_float((int)fl + 1), f, __fsub_rn(1.0f, f), 0.f);
      float d2 = delay2[tid];
      float fl2 = floorf(d2);
      float f2v = __fsub_rn(d2, fl2);
      efo2[tid] = make_float4(__int_as_float((int)fl2 + 1), f2v, __fsub_rn(1.0f, f2v), 0.f);
      w3T[tid * 8 + 5] = f2v;
      w3T[tid * 8 + 6] = __fsub_rn(1.0f, f2v);
      w3T[tid * 8 + 7] = 0.f;
    }
  }
  if (tid < NOUT_) {
    float ss = 0.f;
    for (int c = 0; c < NH_; c++) { float vv = fc3_v[tid * NH_ + c]; ss = __fmaf_rn(vv, vv, ss); }
    float nrm = sqrtf(ss);
    float g = fc3_g[tid];
    for (int c = 0; c < NH_; c++)
      w3T[c * 8 + tid] = 64.0f * __fdiv_rn(mulrn(g, fc3_v[tid * NH_ + c]), nrm);
  }
  if (tid < 3) counts[tid] = 0.f;
  __syncthreads();
  for (int i = tid; i < NH_ * NH_; i += 1024) {
    int o = i >> 7, c = i & 127;
    float wv = 64.0f * __fdiv_rn(mulrn(s_g2[o], fc2_v[i]), s_n2[o]);
    float d1 = delay1[c];
    float f = __fsub_rn(d1, floorf(d1));
    int lane = (o & 31) + 32 * ((c >> 3) & 1);
    int ks = c >> 4, j = c & 7, mt = o >> 5;
    wswz[((size_t)((0 * 4 + mt) * 8 + ks) * 64 + lane) * 8 + j] = f2bf(__fmul_rn(wv, f));
    wswz[((size_t)((1 * 4 + mt) * 8 + ks) * 64 + lane) * 8 + j] =
        f2bf(__fmul_rn(wv, __fsub_rn(1.0f, f)));
  }
}

// ---------------------------------------------------------------------------
// pack: input f32 spikes (B,16,T) -> 16-bit channel masks Xb[b][t] via ballot.
// ---------------------------------------------------------------------------
__global__ __launch_bounds__(256) void pack_kernel(const float* __restrict__ spike,
                                                   uint16_t* __restrict__ Xb) {
  int gw = blockIdx.x * 4 + (threadIdx.x >> 6);
  int lane = threadIdx.x & 63;
  int b = gw >> 5;
  int t = (gw & 31) * 64 + lane;
  const float* sp = spike + (size_t)b * NIN_ * T_ + t;
  uint32_t mask = 0;
#pragma unroll
  for (int c = 0; c < NIN_; c++) {
    unsigned long long bal = __ballot(sp[(size_t)c * T_] != 0.f);
    mask |= (uint32_t)((bal >> lane) & 1ull) << c;
  }
  Xb[(size_t)b * T_ + t] = (uint16_t)mask;
}

// ---------------------------------------------------------------------------
// Shared scanner for the fused kernels: wave 4 scans a t-major 32x128 LDS
// tile; each lane owns rows o=lane and o=lane+64 (2 interleaved chains, no
// shuffles). Emits bit words + popcounts.
// ---------------------------------------------------------------------------
struct ScanState {
  float ua, va, ub, vb, csum;
};

__device__ __forceinline__ void scan_tile(const float* __restrict__ ztb, int lane,
                                          ScanState& st, uint32_t& ma, uint32_t& mb) {
  ma = 0u; mb = 0u;
  float ua = st.ua, va = st.va, ub = st.ub, vb = st.vb;
#pragma unroll
  for (int t = 0; t < 32; t++) {
    float za = ztb[t * 128 + lane];
    float zb = ztb[t * 128 + 64 + lane];
    ua = addrn(mulrn(ALPHA_I_, ua), za);
    va = addrn(mulrn(ALPHA_V_, va), ua);
    bool sa = (va >= THETA_);
    va = sa ? 0.f : va;
    ma |= sa ? (1u << t) : 0u;
    ub = addrn(mulrn(ALPHA_I_, ub), zb);
    vb = addrn(mulrn(ALPHA_V_, vb), ub);
    bool sb2 = (vb >= THETA_);
    vb = sb2 ? 0.f : vb;
    mb |= sb2 ? (1u << t) : 0u;
  }
  st.ua = ua; st.va = va; st.ub = ub; st.vb = vb;
}

// ---------------------------------------------------------------------------
// Fused layer 1: producer waves 0-3 (one MFMA o-tile each) fill the LDS z
// tile; wave 4 scans. Double-buffered, 1 barrier per 32-t group.
// grid (NCHUNK_, B), block 320.
// ---------------------------------------------------------------------------
__global__ __launch_bounds__(320) void fused_layer1(const uint16_t* __restrict__ Xb,
                                                    const uint16_t* __restrict__ w1swz,
                                                    uint32_t* __restrict__ sbits2,
                                                    float* __restrict__ cnt) {
  __shared__ float zt[2 * 32 * 128];
  __shared__ uint2 s_lut[16];
  int tid = threadIdx.x;
  int wv = tid >> 6, lane = tid & 63;
  int hi = lane >> 5, tl = lane & 31;
  int ci = blockIdx.x, b = blockIdx.y;
  lut_init(s_lut, tid);

  bf16x8 wfrag = {};
  if (wv < 4) wfrag = ((const bf16x8*)w1swz)[wv * 64 + lane];
  __syncthreads();

  int wch = (ci == 0) ? 0 : (WARM_ / 32);
  int nch = CHT_ / 32 + wch;
  int chbase0 = ci * CHT_ - wch * 32;
  const uint16_t* xb = Xb + (size_t)b * T_;
  uint32_t* sb = sbits2 + (size_t)b * 68 * NH_;

  ScanState st = {0.f, 0.f, 0.f, 0.f, 0.f};

  auto produce = [&](int g) {
    uint32_t x = xb[chbase0 + g * 32 + tl];
    uint32_t byt = (x >> (8 * hi)) & 0xFFu;
    bf16x8 afr = expand8(s_lut, byt);
    f32x16 acc;
#pragma unroll
    for (int r = 0; r < 16; r++) acc[r] = 0.f;
    acc = __builtin_amdgcn_mfma_f32_32x32x16_bf16(afr, wfrag, acc, 0, 0, 0);
    float* ztb = zt + (g & 1) * 4096;
#pragma unroll
    for (int r = 0; r < 16; r++) {
      int trow = (r & 3) + 8 * (r >> 2) + 4 * hi;
      ztb[trow * 128 + wv * 32 + tl] = acc[r];
    }
  };

  auto consume = [&](int g) {
    uint32_t ma, mb;
    scan_tile(zt + (g & 1) * 4096, lane, st, ma, mb);
    if (g >= wch) {
      int gw = (chbase0 + g * 32) >> 5;
      sb[(2 + gw) * NH_ + lane] = ma;
      sb[(2 + gw) * NH_ + 64 + lane] = mb;
      int pc = __popc(ma) + __popc(mb);
      if (gw == 63) pc -= (int)(ma >> 31) + (int)(mb >> 31);
      st.csum += (float)pc;
    }
  };

  for (int g = 0; g < nch; g++) {
    if (wv < 4) produce(g);
    else if (g > 0) consume(g - 1);
    __syncthreads();
  }
  if (wv == 4) {
    consume(nch - 1);
    if (ci == 0) {
      sb[0 * NH_ + lane] = 0u; sb[0 * NH_ + 64 + lane] = 0u;
      sb[1 * NH_ + lane] = 0u; sb[1 * NH_ + 64 + lane] = 0u;
    }
    if (ci == NCHUNK_ - 1) {
      sb[66 * NH_ + lane] = 0u; sb[66 * NH_ + 64 + lane] = 0u;
      sb[67 * NH_ + lane] = 0u; sb[67 * NH_ + 64 + lane] = 0u;
    }
    float c = st.csum;
    for (int off = 32; off; off >>= 1) c += __shfl_down(c, off, 64);
    if (lane == 0) atomicAdd(cnt, c);
  }
}

// ---------------------------------------------------------------------------
// Fused layer 2: producer waves 0-3 (16 MFMA each from pre-shifted PT bit
// rows, dual accumulators) fill the LDS z tile; wave 4 scans.
// grid (NCHUNK_, B), block 320.
// ---------------------------------------------------------------------------
__global__ __launch_bounds__(320) void fused_layer2(const uint32_t* __restrict__ PTpad,
                                                    const uint16_t* __restrict__ wswz,
                                                    uint32_t* __restrict__ sbits2,
                                                    float* __restrict__ cnt) {
  __shared__ float zt[2 * 32 * 128];
  __shared__ uint2 s_lut[16];
  int tid = threadIdx.x;
  int wv = tid >> 6, lane = tid & 63;
  int hi = lane >> 5, tl = lane & 31;
  int ci = blockIdx.x, b = blockIdx.y;
  lut_init(s_lut, tid);

  bf16x8 wf[8], wo[8];
  if (wv < 4) {
    const bf16x8* wsv = (const bf16x8*)wswz;
#pragma unroll
    for (int ks = 0; ks < 8; ks++) {
      wf[ks] = wsv[((size_t)((0 * 4 + wv) * 8 + ks) * 64) + lane];
      wo[ks] = wsv[((size_t)((1 * 4 + wv) * 8 + ks) * 64) + lane];
    }
  }
  __syncthreads();

  int wch = (ci == 0) ? 0 : (WARM_ / 32);
  int nch = CHT_ / 32 + wch;
  int chbase0 = ci * CHT_ - wch * 32;
  const uint4* pt = (const uint4*)PTpad + (size_t)b * (T_ + 1);
  uint32_t* sb = sbits2 + (size_t)b * 68 * NH_;

  ScanState st = {0.f, 0.f, 0.f, 0.f, 0.f};

  auto produce = [&](int g) {
    uint4 R0 = pt[chbase0 + g * 32 + tl];
    uint4 R1 = pt[chbase0 + g * 32 + tl + 1];
    uint32_t r0w[4] = {R0.x, R0.y, R0.z, R0.w};
    uint32_t r1w[4] = {R1.x, R1.y, R1.z, R1.w};
    f32x16 af, ao;
#pragma unroll
    for (int r = 0; r < 16; r++) { af[r] = 0.f; ao[r] = 0.f; }
#pragma unroll
    for (int ks = 0; ks < 8; ks++) {
      int sh = 16 * (ks & 1) + 8 * hi;
      uint32_t b0 = (r0w[ks >> 1] >> sh) & 0xFFu;  // tap s[t-e-1] -> Wf
      uint32_t b1 = (r1w[ks >> 1] >> sh) & 0xFFu;  // tap s[t-e]   -> Wof
      af = __builtin_amdgcn_mfma_f32_32x32x16_bf16(expand8(s_lut, b0), wf[ks], af, 0, 0, 0);
      ao = __builtin_amdgcn_mfma_f32_32x32x16_bf16(expand8(s_lut, b1), wo[ks], ao, 0, 0, 0);
    }
    float* ztb = zt + (g & 1) * 4096;
#pragma unroll
    for (int r = 0; r < 16; r++) {
      int trow = (r & 3) + 8 * (r >> 2) + 4 * hi;
      ztb[trow * 128 + wv * 32 + tl] = addrn(af[r], ao[r]);
    }
  };

  auto consume = [&](int g) {
    uint32_t ma, mb;
    scan_tile(zt + (g & 1) * 4096, lane, st, ma, mb);
    if (g >= wch) {
      int gw = (chbase0 + g * 32) >> 5;
      sb[(2 + gw) * NH_ + lane] = ma;
      sb[(2 + gw) * NH_ + 64 + lane] = mb;
      int pc = __popc(ma) + __popc(mb);
      if (gw == 63) pc -= (int)(ma >> 31) + (int)(mb >> 31);
      st.csum += (float)pc;
    }
  };

  for (int g = 0; g < nch; g++) {
    if (wv < 4) produce(g);
    else if (g > 0) consume(g - 1);
    __syncthreads();
  }
  if (wv == 4) {
    consume(nch - 1);
    if (ci == 0) {
      sb[0 * NH_ + lane] = 0u; sb[0 * NH_ + 64 + lane] = 0u;
      sb[1 * NH_ + lane] = 0u; sb[1 * NH_ + 64 + lane] = 0u;
    }
    if (ci == NCHUNK_ - 1) {
      sb[66 * NH_ + lane] = 0u; sb[66 * NH_ + 64 + lane] = 0u;
      sb[67 * NH_ + lane] = 0u; sb[67 * NH_ + 64 + lane] = 0u;
    }
    float c = st.csum;
    for (int off = 32; off; off >>= 1) c += __shfl_down(c, off, 64);
    if (lane == 0) atomicAdd(cnt, c);
  }
}

// ---------------------------------------------------------------------------
// bit transpose + delay pre-shift: PTpad[b][1+t] row (128 bits) bit c =
// s[c][t - e_c]; PTpad[b][0] = 0. Reads sbits2[b][slot][o] layout.
// ---------------------------------------------------------------------------
__global__ __launch_bounds__(256) void transpose_kernel(const uint32_t* __restrict__ sbits2,
                                                        const float4* __restrict__ efo,
                                                        uint32_t* __restrict__ PTpad) {
  __shared__ uint32_t rows[NH_ * 69];
  int tid = threadIdx.x;
  int b = blockIdx.x;
  const uint32_t* src = sbits2 + (size_t)b * 68 * NH_;
  for (int i = tid; i < 68 * NH_; i += 256) {
    int w = i >> 7, c = i & 127;
    rows[c * 69 + w] = src[i];
  }
  __syncthreads();

  uint4* outp = (uint4*)PTpad + (size_t)b * (T_ + 1);
  if (tid == 0) outp[0] = make_uint4(0u, 0u, 0u, 0u);

  int t0 = tid * 8;
  uint32_t wacc[8][4];
#pragma unroll
  for (int i = 0; i < 8; i++)
#pragma unroll
    for (int j = 0; j < 4; j++) wacc[i][j] = 0u;

#pragma unroll
  for (int c = 0; c < NH_; c++) {
    int e = __float_as_int(efo[c].x);
    int bitpos0 = t0 - e;
    int wi = bitpos0 >> 5;
    int sh = bitpos0 & 31;
    uint32_t lo = rows[c * 69 + 2 + wi];
    uint32_t hi2 = rows[c * 69 + 3 + wi];
    uint32_t bits8 = (uint32_t)(((((unsigned long long)hi2 << 32) | lo) >> sh)) & 0xFFu;
#pragma unroll
    for (int i = 0; i < 8; i++)
      wacc[i][c >> 5] |= ((bits8 >> i) & 1u) << (c & 31);
  }

#pragma unroll
  for (int i = 0; i < 8; i++)
    outp[1 + t0 + i] = make_uint4(wacc[i][0], wacc[i][1], wacc[i][2], wacc[i][3]);
}

// ---------------------------------------------------------------------------
// gemm3 (vector): 5 outputs from pre-shifted PT rows.
// ---------------------------------------------------------------------------
__global__ __launch_bounds__(256) void gemm3_kernel(const uint32_t* __restrict__ PTpad,
                                                    const float* __restrict__ w3T,
                                                    float* __restrict__ z) {
  int tid = threadIdx.x;
  int t = blockIdx.x * 256 + tid;
  int b = blockIdx.y;
  const uint4* pt = (const uint4*)PTpad + (size_t)b * (T_ + 1);
  uint4 R0 = pt[t];
  uint4 R1 = pt[t + 1];
  uint32_t r0w[4] = {R0.x, R0.y, R0.z, R0.w};
  uint32_t r1w[4] = {R1.x, R1.y, R1.z, R1.w};

  float acc[NOUT_];
#pragma unroll
  for (int o = 0; o < NOUT_; o++) acc[o] = 0.f;

#pragma unroll
  for (int c = 0; c < NH_; c++) {
    const float* wc = w3T + (c << 3);
    float f = wc[5], omf = wc[6];
    float fb0 = (float)((r0w[c >> 5] >> (c & 31)) & 1u);
    float fb1 = (float)((r1w[c >> 5] >> (c & 31)) & 1u);
    float val = __fmaf_rn(omf, fb1, __fmul_rn(f, fb0));
#pragma unroll
    for (int o = 0; o < NOUT_; o++) acc[o] = __fmaf_rn(wc[o], val, acc[o]);
  }

#pragma unroll
  for (int o = 0; o < NOUT_; o++)
    z[((size_t)b * NOUT_ + o) * T_ + t] = acc[o];
}

// ---------------------------------------------------------------------------
// Chunked layer-3 scan: thread per (chunk, b, o); 96-step warmup; f32 SHIFTED
// output (out[t]=s[t-1]) via float4 stores; count excludes t=T-1.
// ---------------------------------------------------------------------------
__global__ __launch_bounds__(256) void scan3_kernel(const float* __restrict__ z3,
                                                    float* __restrict__ out,
                                                    float* __restrict__ cnt) {
  int id = blockIdx.x * 256 + threadIdx.x;
  int row = id % (B_ * NOUT_);
  int ci = id / (B_ * NOUT_);
  int tstart = ci * CHT_;
  int t0 = (ci == 0) ? 0 : tstart - WARM_;
  const float4* zp4 = (const float4*)(z3 + (size_t)row * T_);

  float u = 0.f, v = 0.f, carry = 0.f;
  int cnt_i = 0;
  for (int gg = t0 / 16; gg < tstart / 16; gg++) {
#pragma unroll
    for (int q = 0; q < 4; q++) {
      float4 cv = zp4[gg * 4 + q];
      float zv[4] = {cv.x, cv.y, cv.z, cv.w};
#pragma unroll
      for (int j = 0; j < 4; j++) {
        u = addrn(mulrn(ALPHA_I_, u), zv[j]);
        v = addrn(mulrn(ALPHA_V_, v), u);
        bool s = (v >= THETA_);
        v = s ? 0.f : v;
        carry = s ? 1.f : 0.f;
      }
    }
  }
  float4* op4 = (float4*)(out + (size_t)row * T_ + tstart);
  for (int gg = 0; gg < CHT_ / 16; gg++) {
    float sarr[16];
#pragma unroll
    for (int q = 0; q < 4; q++) {
      float4 cv = zp4[(tstart / 16 + gg) * 4 + q];
      float zv[4] = {cv.x, cv.y, cv.z, cv.w};
#pragma unroll
      for (int j = 0; j < 4; j++) {
        u = addrn(mulrn(ALPHA_I_, u), zv[j]);
        v = addrn(mulrn(ALPHA_V_, v), u);
        bool s = (v >= THETA_);
        v = s ? 0.f : v;
        sarr[q * 4 + j] = s ? 1.f : 0.f;
      }
    }
#pragma unroll
    for (int k = 0; k < 16; k++) {
      int t = tstart + gg * 16 + k;
      if (t < T_ - 1) cnt_i += (sarr[k] != 0.f) ? 1 : 0;
    }
    op4[gg * 4 + 0] = make_float4(carry, sarr[0], sarr[1], sarr[2]);
    op4[gg * 4 + 1] = make_float4(sarr[3], sarr[4], sarr[5], sarr[6]);
    op4[gg * 4 + 2] = make_float4(sarr[7], sarr[8], sarr[9], sarr[10]);
    op4[gg * 4 + 3] = make_float4(sarr[11], sarr[12], sarr[13], sarr[14]);
    carry = sarr[15];
  }
  float c = (float)cnt_i;
  for (int off = 32; off; off >>= 1) c += __shfl_down(c, off, 64);
  if ((threadIdx.x & 63) == 0) atomicAdd(cnt, c);
}

// ---------------------------------------------------------------------------
extern "C" void kernel_launch(void* const* d_in, const int* in_sizes, int n_in,
                              void* d_out, int out_size, void* d_ws, size_t ws_size,
                              hipStream_t stream) {
  (void)in_sizes; (void)n_in; (void)out_size; (void)ws_size;
  const float* spike  = (const float*)d_in[0];
  const float* fc1_v  = (const float*)d_in[1];
  const float* fc1_g  = (const float*)d_in[2];
  const float* fc2_v  = (const float*)d_in[3];
  const float* fc2_g  = (const float*)d_in[4];
  const float* fc3_v  = (const float*)d_in[5];
  const float* fc3_g  = (const float*)d_in[6];
  const float* delay1 = (const float*)d_in[7];
  const float* delay2 = (const float*)d_in[8];
  float* out = (float*)d_out;

  float* ws = (float*)d_ws;
  float* w3T       = ws;                         // 1024 f
  float4* efo1     = (float4*)(ws + 1024);       // 512 f
  float4* efo2     = (float4*)(ws + 1536);       // 512 f
  uint16_t* w1swz  = (uint16_t*)(ws + 2048);     // 2048 u16 = 1024 f
  uint16_t* wswz   = (uint16_t*)(ws + 3072);     // 32768 u16 = 16384 f
  uint16_t* Xb     = (uint16_t*)(ws + 19456);    // B*T u16 = 131072 f
  uint32_t* sbits2 = (uint32_t*)(ws + 150528);   // B*68*128 u32
  uint32_t* PTpad  = (uint32_t*)(ws + 1264640);  // B*(T+1)*4 u32, 16B-aligned
  float* z3        = ws + 2313728;               // B*5*T f32
  float* counts = out + (size_t)B_ * NOUT_ * T_;

  prep_kernel<<<1, 1024, 0, stream>>>(fc1_v, fc1_g, fc2_v, fc2_g, fc3_v, fc3_g,
                                      delay1, delay2, w1swz, wswz, w3T, efo1, efo2, counts);

  pack_kernel<<<dim3(B_ * T_ / 64 / 4), 256, 0, stream>>>(spike, Xb);

  fused_layer1<<<dim3(NCHUNK_, B_), 320, 0, stream>>>(Xb, w1swz, sbits2, counts + 0);
  transpose_kernel<<<dim3(B_), 256, 0, stream>>>(sbits2, efo1, PTpad);

  fused_layer2<<<dim3(NCHUNK_, B_), 320, 0, stream>>>(PTpad, wswz, sbits2, counts + 1);
  transpose_kernel<<<dim3(B_), 256, 0, stream>>>(sbits2, efo2, PTpad);

  gemm3_kernel<<<dim3(T_ / 256, B_), 256, 0, stream>>>(PTpad, w3T, z3);
  scan3_kernel<<<dim3(NCHUNK_ * B_ * NOUT_ / 256), 256, 0, stream>>>(z3, out, counts + 2);
}

// Round 8
// 259.361 us; speedup vs baseline: 1.1904x; 1.1280x over previous
//
#include <hip/hip_runtime.h>
#include <cstdint>

#define B_    128
#define T_    2048
#define NIN_  16
#define NH_   128
#define NOUT_ 5

#define ALPHA_I_ 0.75f
#define ALPHA_V_ 0.96875f
#define THETA_   64.0f

#define NCHUNK_ 8
#define CHT_    256     // data timesteps per chunk
#define WARM_   96      // warmup timesteps (3 sub-chunks of 32)

typedef short bf16x8 __attribute__((ext_vector_type(8)));
typedef float f32x16 __attribute__((ext_vector_type(16)));

__device__ __forceinline__ float mulrn(float a, float b) { return __fmul_rn(a, b); }
__device__ __forceinline__ float addrn(float a, float b) { return __fadd_rn(a, b); }

__device__ __forceinline__ uint16_t f2bf(float x) {  // RNE f32->bf16
  uint32_t u = __float_as_uint(x);
  return (uint16_t)((u + 0x7FFFu + ((u >> 16) & 1u)) >> 16);
}

// nibble LUT (16 x uint2 in LDS, bank-conflict-free): bit j -> bf16 1.0/0.0
__device__ __forceinline__ bf16x8 expand8(const uint2* __restrict__ lut, uint32_t byt) {
  uint2 lo = lut[byt & 15u];
  uint2 h  = lut[byt >> 4];
  union { uint32_t w[4]; bf16x8 f; } r;
  r.w[0] = lo.x; r.w[1] = lo.y; r.w[2] = h.x; r.w[3] = h.y;
  return r.f;
}

__device__ __forceinline__ void lut_init(uint2* s_lut, int tid) {
  if (tid < 16) {
    uint32_t w0 = ((tid & 1) ? 0x3F80u : 0u) | ((tid & 2) ? 0x3F800000u : 0u);
    uint32_t w1 = ((tid & 4) ? 0x3F80u : 0u) | ((tid & 8) ? 0x3F800000u : 0u);
    s_lut[tid] = make_uint2(w0, w1);
  }
}

// ---------------------------------------------------------------------------
// prep (1024 threads): weight_norm (x64 folded). w1swz / wswz in the
// R5-R7-verified MFMA B-fragment swizzle. w3T[c][0..4]=w3, [5]=f2,[6]=1-f2.
// efo: e=floor(d)+1 (includes delay_shift1's +1). Zero counts.
// ---------------------------------------------------------------------------
__global__ __launch_bounds__(1024) void prep_kernel(
    const float* __restrict__ fc1_v, const float* __restrict__ fc1_g,
    const float* __restrict__ fc2_v, const float* __restrict__ fc2_g,
    const float* __restrict__ fc3_v, const float* __restrict__ fc3_g,
    const float* __restrict__ delay1, const float* __restrict__ delay2,
    uint16_t* __restrict__ w1swz, uint16_t* __restrict__ wswz,
    float* __restrict__ w3T, float4* __restrict__ efo1, float4* __restrict__ efo2,
    float* __restrict__ counts) {
  __shared__ float s_g2[NH_], s_n2[NH_];
  int tid = threadIdx.x;
  if (tid < NH_) {
    {
      float ss = 0.f;
      for (int c = 0; c < NH_; c++) { float vv = fc2_v[tid * NH_ + c]; ss = __fmaf_rn(vv, vv, ss); }
      s_n2[tid] = sqrtf(ss);
      s_g2[tid] = fc2_g[tid];
    }
    {
      float ss = 0.f;
      for (int c = 0; c < NIN_; c++) { float vv = fc1_v[tid * NIN_ + c]; ss = __fmaf_rn(vv, vv, ss); }
      float nrm = sqrtf(ss);
      float g = fc1_g[tid];
      int mt = tid >> 5;
      for (int c = 0; c < NIN_; c++) {
        float wv = 64.0f * __fdiv_rn(mulrn(g, fc1_v[tid * NIN_ + c]), nrm);
        int lane = (tid & 31) + 32 * ((c >> 3) & 1);
        int j = c & 7;
        w1swz[(mt * 64 + lane) * 8 + j] = f2bf(wv);
      }
    }
    {
      float d1 = delay1[tid];
      float fl = floorf(d1);
      float f = __fsub_rn(d1, fl);
      efo1[tid] = make_float4(__int_as_float((int)fl + 1), f, __fsub_rn(1.0f, f), 0.f);
      float d2 = delay2[tid];
      float fl2 = floorf(d2);
      float f2v = __fsub_rn(d2, fl2);
      efo2[tid] = make_float4(__int_as_float((int)fl2 + 1), f2v, __fsub_rn(1.0f, f2v), 0.f);
      w3T[tid * 8 + 5] = f2v;
      w3T[tid * 8 + 6] = __fsub_rn(1.0f, f2v);
      w3T[tid * 8 + 7] = 0.f;
    }
  }
  if (tid < NOUT_) {
    float ss = 0.f;
    for (int c = 0; c < NH_; c++) { float vv = fc3_v[tid * NH_ + c]; ss = __fmaf_rn(vv, vv, ss); }
    float nrm = sqrtf(ss);
    float g = fc3_g[tid];
    for (int c = 0; c < NH_; c++)
      w3T[c * 8 + tid] = 64.0f * __fdiv_rn(mulrn(g, fc3_v[tid * NH_ + c]), nrm);
  }
  if (tid < 3) counts[tid] = 0.f;
  __syncthreads();
  for (int i = tid; i < NH_ * NH_; i += 1024) {
    int o = i >> 7, c = i & 127;
    float wv = 64.0f * __fdiv_rn(mulrn(s_g2[o], fc2_v[i]), s_n2[o]);
    float d1 = delay1[c];
    float f = __fsub_rn(d1, floorf(d1));
    int lane = (o & 31) + 32 * ((c >> 3) & 1);
    int ks = c >> 4, j = c & 7, mt = o >> 5;
    wswz[((size_t)((0 * 4 + mt) * 8 + ks) * 64 + lane) * 8 + j] = f2bf(__fmul_rn(wv, f));
    wswz[((size_t)((1 * 4 + mt) * 8 + ks) * 64 + lane) * 8 + j] =
        f2bf(__fmul_rn(wv, __fsub_rn(1.0f, f)));
  }
}

// ---------------------------------------------------------------------------
// pack: input f32 spikes (B,16,T) -> 16-bit channel masks Xb[b][t] via ballot.
// ---------------------------------------------------------------------------
__global__ __launch_bounds__(256) void pack_kernel(const float* __restrict__ spike,
                                                   uint16_t* __restrict__ Xb) {
  int gw = blockIdx.x * 4 + (threadIdx.x >> 6);
  int lane = threadIdx.x & 63;
  int b = gw >> 5;
  int t = (gw & 31) * 64 + lane;
  const float* sp = spike + (size_t)b * NIN_ * T_ + t;
  uint32_t mask = 0;
#pragma unroll
  for (int c = 0; c < NIN_; c++) {
    unsigned long long bal = __ballot(sp[(size_t)c * T_] != 0.f);
    mask |= (uint32_t)((bal >> lane) & 1ull) << c;
  }
  Xb[(size_t)b * T_ + t] = (uint16_t)mask;
}

// ---------------------------------------------------------------------------
// Gather a wave's 2-tile (tiles A,B; 64o x 32t) MFMA result so that every
// lane holds all 32 t for one o, via 16 batched shfl_xor(32) (NOT in the
// scan chain). D layout (R6/R7-verified): row t = (r&3)+8*(r>>2)+4*hi,
// col o = lane&31. evenQ[r]/oddQ[r] = values for even/odd t-quads.
// Then scan 32 steps fully in-register; m bit t = spike. o = pair*64+lane.
// ---------------------------------------------------------------------------
#define GATHER_AND_SCAN(aA, aB, hi, u, v, m)                               \
  {                                                                        \
    float evenQ[16], oddQ[16];                                             \
    _Pragma("unroll") for (int r = 0; r < 16; r++) {                       \
      float tmp = hi ? aA[r] : aB[r];                                      \
      float rcv = __shfl_xor(tmp, 32, 64);                                 \
      evenQ[r] = hi ? rcv : aA[r];                                         \
      oddQ[r] = hi ? aB[r] : rcv;                                          \
    }                                                                      \
    m = 0u;                                                                \
    _Pragma("unroll") for (int t = 0; t < 32; t++) {                       \
      int q = t >> 2;                                                      \
      int base = 4 * (q >> 1) + (t & 3);                                   \
      float z = (q & 1) ? oddQ[base] : evenQ[base];                        \
      u = addrn(mulrn(ALPHA_I_, u), z);                                    \
      v = addrn(mulrn(ALPHA_V_, v), u);                                    \
      bool sbit = (v >= THETA_);                                           \
      v = sbit ? 0.f : v;                                                  \
      m |= sbit ? (1u << t) : 0u;                                          \
    }                                                                      \
  }

// ---------------------------------------------------------------------------
// Fused layer 1: wave = 2 o-tiles (shared A-frag from input bits, 2 MFMA),
// gather + in-register scan, coalesced bit store + counts. Waves independent.
// grid (NCHUNK_, B), block 128 (2 waves = o pairs {0-63},{64-127}).
// ---------------------------------------------------------------------------
__global__ __launch_bounds__(128, 2) void fused_layer1(const uint16_t* __restrict__ Xb,
                                                       const uint16_t* __restrict__ w1swz,
                                                       uint32_t* __restrict__ sbits2,
                                                       float* __restrict__ cnt) {
  __shared__ uint2 s_lut[16];
  int tid = threadIdx.x;
  int pair = tid >> 6, lane = tid & 63;
  int hi = lane >> 5, tl = lane & 31;
  int ci = blockIdx.x, b = blockIdx.y;
  lut_init(s_lut, tid);
  const bf16x8* w1v = (const bf16x8*)w1swz;
  bf16x8 wA = w1v[(pair * 2 + 0) * 64 + lane];
  bf16x8 wB = w1v[(pair * 2 + 1) * 64 + lane];
  __syncthreads();

  int wch = (ci == 0) ? 0 : (WARM_ / 32);
  int nch = CHT_ / 32 + wch;
  int chbase0 = ci * CHT_ - wch * 32;
  const uint16_t* xb = Xb + (size_t)b * T_;
  uint32_t* sb = sbits2 + (size_t)b * 68 * NH_;

  float u = 0.f, v = 0.f, csum = 0.f;
  uint32_t x = xb[chbase0 + tl];
  for (int g = 0; g < nch; g++) {
    uint32_t xn = (g + 1 < nch) ? (uint32_t)xb[chbase0 + (g + 1) * 32 + tl] : 0u;
    uint32_t byt = (x >> (8 * hi)) & 0xFFu;
    bf16x8 e = expand8(s_lut, byt);
    f32x16 aA, aB;
#pragma unroll
    for (int r = 0; r < 16; r++) { aA[r] = 0.f; aB[r] = 0.f; }
    aA = __builtin_amdgcn_mfma_f32_32x32x16_bf16(e, wA, aA, 0, 0, 0);
    aB = __builtin_amdgcn_mfma_f32_32x32x16_bf16(e, wB, aB, 0, 0, 0);
    uint32_t m;
    GATHER_AND_SCAN(aA, aB, hi, u, v, m);
    if (g >= wch) {
      int gw = (chbase0 + g * 32) >> 5;
      sb[(2 + gw) * NH_ + pair * 64 + lane] = m;
      int pc = __popc(m);
      if (gw == 63) pc -= (int)(m >> 31);
      csum += (float)pc;
    }
    x = xn;
  }
  if (ci == 0) { sb[0 * NH_ + pair * 64 + lane] = 0u; sb[1 * NH_ + pair * 64 + lane] = 0u; }
  if (ci == NCHUNK_ - 1) { sb[66 * NH_ + pair * 64 + lane] = 0u; sb[67 * NH_ + pair * 64 + lane] = 0u; }
  for (int off = 32; off; off >>= 1) csum += __shfl_down(csum, off, 64);
  if (lane == 0) atomicAdd(cnt, csum);
}

// ---------------------------------------------------------------------------
// Fused layer 2: wave = 2 o-tiles (shared A-frags: 2 delay taps from the
// pre-shifted PT rows; per ks: 2 expand + 4 MFMA), gather + in-register scan.
// grid (NCHUNK_, B), block 128.
// ---------------------------------------------------------------------------
__global__ __launch_bounds__(128, 2) void fused_layer2(const uint32_t* __restrict__ PTpad,
                                                       const uint16_t* __restrict__ wswz,
                                                       uint32_t* __restrict__ sbits2,
                                                       float* __restrict__ cnt) {
  __shared__ uint2 s_lut[16];
  int tid = threadIdx.x;
  int pair = tid >> 6, lane = tid & 63;
  int hi = lane >> 5, tl = lane & 31;
  int ci = blockIdx.x, b = blockIdx.y;
  lut_init(s_lut, tid);
  const bf16x8* wsv = (const bf16x8*)wswz;
  int mtA = pair * 2, mtB = pair * 2 + 1;
  bf16x8 wfA[8], woA[8], wfB[8], woB[8];
#pragma unroll
  for (int ks = 0; ks < 8; ks++) {
    wfA[ks] = wsv[((size_t)((0 * 4 + mtA) * 8 + ks) * 64) + lane];
    woA[ks] = wsv[((size_t)((1 * 4 + mtA) * 8 + ks) * 64) + lane];
    wfB[ks] = wsv[((size_t)((0 * 4 + mtB) * 8 + ks) * 64) + lane];
    woB[ks] = wsv[((size_t)((1 * 4 + mtB) * 8 + ks) * 64) + lane];
  }
  __syncthreads();

  int wch = (ci == 0) ? 0 : (WARM_ / 32);
  int nch = CHT_ / 32 + wch;
  int chbase0 = ci * CHT_ - wch * 32;
  const uint4* pt = (const uint4*)PTpad + (size_t)b * (T_ + 1);
  uint32_t* sb = sbits2 + (size_t)b * 68 * NH_;

  float u = 0.f, v = 0.f, csum = 0.f;
  uint4 R0 = pt[chbase0 + tl];
  uint4 R1 = pt[chbase0 + tl + 1];
  for (int g = 0; g < nch; g++) {
    uint4 R0n = R0, R1n = R1;
    if (g + 1 < nch) {
      R0n = pt[chbase0 + (g + 1) * 32 + tl];
      R1n = pt[chbase0 + (g + 1) * 32 + tl + 1];
    }
    uint32_t r0w[4] = {R0.x, R0.y, R0.z, R0.w};
    uint32_t r1w[4] = {R1.x, R1.y, R1.z, R1.w};
    f32x16 aA, aB;
#pragma unroll
    for (int r = 0; r < 16; r++) { aA[r] = 0.f; aB[r] = 0.f; }
#pragma unroll
    for (int ks = 0; ks < 8; ks++) {
      int sh = 16 * (ks & 1) + 8 * hi;
      uint32_t b0 = (r0w[ks >> 1] >> sh) & 0xFFu;  // tap s[t-e-1] -> Wf
      uint32_t b1 = (r1w[ks >> 1] >> sh) & 0xFFu;  // tap s[t-e]   -> Wof
      bf16x8 e0 = expand8(s_lut, b0);
      bf16x8 e1 = expand8(s_lut, b1);
      aA = __builtin_amdgcn_mfma_f32_32x32x16_bf16(e0, wfA[ks], aA, 0, 0, 0);
      aA = __builtin_amdgcn_mfma_f32_32x32x16_bf16(e1, woA[ks], aA, 0, 0, 0);
      aB = __builtin_amdgcn_mfma_f32_32x32x16_bf16(e0, wfB[ks], aB, 0, 0, 0);
      aB = __builtin_amdgcn_mfma_f32_32x32x16_bf16(e1, woB[ks], aB, 0, 0, 0);
    }
    uint32_t m;
    GATHER_AND_SCAN(aA, aB, hi, u, v, m);
    if (g >= wch) {
      int gw = (chbase0 + g * 32) >> 5;
      sb[(2 + gw) * NH_ + pair * 64 + lane] = m;
      int pc = __popc(m);
      if (gw == 63) pc -= (int)(m >> 31);
      csum += (float)pc;
    }
    R0 = R0n; R1 = R1n;
  }
  if (ci == 0) { sb[0 * NH_ + pair * 64 + lane] = 0u; sb[1 * NH_ + pair * 64 + lane] = 0u; }
  if (ci == NCHUNK_ - 1) { sb[66 * NH_ + pair * 64 + lane] = 0u; sb[67 * NH_ + pair * 64 + lane] = 0u; }
  for (int off = 32; off; off >>= 1) csum += __shfl_down(csum, off, 64);
  if (lane == 0) atomicAdd(cnt, csum);
}

// ---------------------------------------------------------------------------
// bit transpose + delay pre-shift: PTpad[b][1+t] row (128 bits) bit c =
// s[c][t - e_c]; PTpad[b][0] = 0. Reads sbits2[b][slot][o] layout.
// ---------------------------------------------------------------------------
__global__ __launch_bounds__(256) void transpose_kernel(const uint32_t* __restrict__ sbits2,
                                                        const float4* __restrict__ efo,
                                                        uint32_t* __restrict__ PTpad) {
  __shared__ uint32_t rows[NH_ * 69];
  int tid = threadIdx.x;
  int b = blockIdx.x;
  const uint32_t* src = sbits2 + (size_t)b * 68 * NH_;
  for (int i = tid; i < 68 * NH_; i += 256) {
    int w = i >> 7, c = i & 127;
    rows[c * 69 + w] = src[i];
  }
  __syncthreads();

  uint4* outp = (uint4*)PTpad + (size_t)b * (T_ + 1);
  if (tid == 0) outp[0] = make_uint4(0u, 0u, 0u, 0u);

  int t0 = tid * 8;
  uint32_t wacc[8][4];
#pragma unroll
  for (int i = 0; i < 8; i++)
#pragma unroll
    for (int j = 0; j < 4; j++) wacc[i][j] = 0u;

#pragma unroll
  for (int c = 0; c < NH_; c++) {
    int e = __float_as_int(efo[c].x);
    int bitpos0 = t0 - e;
    int wi = bitpos0 >> 5;
    int sh = bitpos0 & 31;
    uint32_t lo = rows[c * 69 + 2 + wi];
    uint32_t hi2 = rows[c * 69 + 3 + wi];
    uint32_t bits8 = (uint32_t)(((((unsigned long long)hi2 << 32) | lo) >> sh)) & 0xFFu;
#pragma unroll
    for (int i = 0; i < 8; i++)
      wacc[i][c >> 5] |= ((bits8 >> i) & 1u) << (c & 31);
  }

#pragma unroll
  for (int i = 0; i < 8; i++)
    outp[1 + t0 + i] = make_uint4(wacc[i][0], wacc[i][1], wacc[i][2], wacc[i][3]);
}

// ---------------------------------------------------------------------------
// gemm3 (vector): 5 outputs from pre-shifted PT rows.
// ---------------------------------------------------------------------------
__global__ __launch_bounds__(256) void gemm3_kernel(const uint32_t* __restrict__ PTpad,
                                                    const float* __restrict__ w3T,
                                                    float* __restrict__ z) {
  int tid = threadIdx.x;
  int t = blockIdx.x * 256 + tid;
  int b = blockIdx.y;
  const uint4* pt = (const uint4*)PTpad + (size_t)b * (T_ + 1);
  uint4 R0 = pt[t];
  uint4 R1 = pt[t + 1];
  uint32_t r0w[4] = {R0.x, R0.y, R0.z, R0.w};
  uint32_t r1w[4] = {R1.x, R1.y, R1.z, R1.w};

  float acc[NOUT_];
#pragma unroll
  for (int o = 0; o < NOUT_; o++) acc[o] = 0.f;

#pragma unroll
  for (int c = 0; c < NH_; c++) {
    const float* wc = w3T + (c << 3);
    float f = wc[5], omf = wc[6];
    float fb0 = (float)((r0w[c >> 5] >> (c & 31)) & 1u);
    float fb1 = (float)((r1w[c >> 5] >> (c & 31)) & 1u);
    float val = __fmaf_rn(omf, fb1, __fmul_rn(f, fb0));
#pragma unroll
    for (int o = 0; o < NOUT_; o++) acc[o] = __fmaf_rn(wc[o], val, acc[o]);
  }

#pragma unroll
  for (int o = 0; o < NOUT_; o++)
    z[((size_t)b * NOUT_ + o) * T_ + t] = acc[o];
}

// ---------------------------------------------------------------------------
// Chunked layer-3 scan: thread per (chunk, b, o); 96-step warmup; f32 SHIFTED
// output (out[t]=s[t-1]) via float4 stores; count excludes t=T-1.
// ---------------------------------------------------------------------------
__global__ __launch_bounds__(256) void scan3_kernel(const float* __restrict__ z3,
                                                    float* __restrict__ out,
                                                    float* __restrict__ cnt) {
  int id = blockIdx.x * 256 + threadIdx.x;
  int row = id % (B_ * NOUT_);
  int ci = id / (B_ * NOUT_);
  int tstart = ci * CHT_;
  int t0 = (ci == 0) ? 0 : tstart - WARM_;
  const float4* zp4 = (const float4*)(z3 + (size_t)row * T_);

  float u = 0.f, v = 0.f, carry = 0.f;
  int cnt_i = 0;
  for (int gg = t0 / 16; gg < tstart / 16; gg++) {
#pragma unroll
    for (int q = 0; q < 4; q++) {
      float4 cv = zp4[gg * 4 + q];
      float zv[4] = {cv.x, cv.y, cv.z, cv.w};
#pragma unroll
      for (int j = 0; j < 4; j++) {
        u = addrn(mulrn(ALPHA_I_, u), zv[j]);
        v = addrn(mulrn(ALPHA_V_, v), u);
        bool s = (v >= THETA_);
        v = s ? 0.f : v;
        carry = s ? 1.f : 0.f;
      }
    }
  }
  float4* op4 = (float4*)(out + (size_t)row * T_ + tstart);
  for (int gg = 0; gg < CHT_ / 16; gg++) {
    float sarr[16];
#pragma unroll
    for (int q = 0; q < 4; q++) {
      float4 cv = zp4[(tstart / 16 + gg) * 4 + q];
      float zv[4] = {cv.x, cv.y, cv.z, cv.w};
#pragma unroll
      for (int j = 0; j < 4; j++) {
        u = addrn(mulrn(ALPHA_I_, u), zv[j]);
        v = addrn(mulrn(ALPHA_V_, v), u);
        bool s = (v >= THETA_);
        v = s ? 0.f : v;
        sarr[q * 4 + j] = s ? 1.f : 0.f;
      }
    }
#pragma unroll
    for (int k = 0; k < 16; k++) {
      int t = tstart + gg * 16 + k;
      if (t < T_ - 1) cnt_i += (sarr[k] != 0.f) ? 1 : 0;
    }
    op4[gg * 4 + 0] = make_float4(carry, sarr[0], sarr[1], sarr[2]);
    op4[gg * 4 + 1] = make_float4(sarr[3], sarr[4], sarr[5], sarr[6]);
    op4[gg * 4 + 2] = make_float4(sarr[7], sarr[8], sarr[9], sarr[10]);
    op4[gg * 4 + 3] = make_float4(sarr[11], sarr[12], sarr[13], sarr[14]);
    carry = sarr[15];
  }
  float c = (float)cnt_i;
  for (int off = 32; off; off >>= 1) c += __shfl_down(c, off, 64);
  if ((threadIdx.x & 63) == 0) atomicAdd(cnt, c);
}

// ---------------------------------------------------------------------------
extern "C" void kernel_launch(void* const* d_in, const int* in_sizes, int n_in,
                              void* d_out, int out_size, void* d_ws, size_t ws_size,
                              hipStream_t stream) {
  (void)in_sizes; (void)n_in; (void)out_size; (void)ws_size;
  const float* spike  = (const float*)d_in[0];
  const float* fc1_v  = (const float*)d_in[1];
  const float* fc1_g  = (const float*)d_in[2];
  const float* fc2_v  = (const float*)d_in[3];
  const float* fc2_g  = (const float*)d_in[4];
  const float* fc3_v  = (const float*)d_in[5];
  const float* fc3_g  = (const float*)d_in[6];
  const float* delay1 = (const float*)d_in[7];
  const float* delay2 = (const float*)d_in[8];
  float* out = (float*)d_out;

  float* ws = (float*)d_ws;
  float* w3T       = ws;                         // 1024 f
  float4* efo1     = (float4*)(ws + 1024);       // 512 f
  float4* efo2     = (float4*)(ws + 1536);       // 512 f
  uint16_t* w1swz  = (uint16_t*)(ws + 2048);     // 2048 u16 = 1024 f
  uint16_t* wswz   = (uint16_t*)(ws + 3072);     // 32768 u16 = 16384 f
  uint16_t* Xb     = (uint16_t*)(ws + 19456);    // B*T u16 = 131072 f
  uint32_t* sbits2 = (uint32_t*)(ws + 150528);   // B*68*128 u32
  uint32_t* PTpad  = (uint32_t*)(ws + 1264640);  // B*(T+1)*4 u32, 16B-aligned
  float* z3        = ws + 2313728;               // B*5*T f32
  float* counts = out + (size_t)B_ * NOUT_ * T_;

  prep_kernel<<<1, 1024, 0, stream>>>(fc1_v, fc1_g, fc2_v, fc2_g, fc3_v, fc3_g,
                                      delay1, delay2, w1swz, wswz, w3T, efo1, efo2, counts);

  pack_kernel<<<dim3(B_ * T_ / 64 / 4), 256, 0, stream>>>(spike, Xb);

  fused_layer1<<<dim3(NCHUNK_, B_), 128, 0, stream>>>(Xb, w1swz, sbits2, counts + 0);
  transpose_kernel<<<dim3(B_), 256, 0, stream>>>(sbits2, efo1, PTpad);

  fused_layer2<<<dim3(NCHUNK_, B_), 128, 0, stream>>>(PTpad, wswz, sbits2, counts + 1);
  transpose_kernel<<<dim3(B_), 256, 0, stream>>>(sbits2, efo2, PTpad);

  gemm3_kernel<<<dim3(T_ / 256, B_), 256, 0, stream>>>(PTpad, w3T, z3);
  scan3_kernel<<<dim3(NCHUNK_ * B_ * NOUT_ / 256), 256, 0, stream>>>(z3, out, counts + 2);
}

// Round 10
// 257.778 us; speedup vs baseline: 1.1977x; 1.0061x over previous
//
#include <hip/hip_runtime.h>
#include <cstdint>

#define B_    128
#define T_    2048
#define NIN_  16
#define NH_   128
#define NOUT_ 5

#define ALPHA_I_ 0.75f
#define ALPHA_V_ 0.96875f
#define THETA_   64.0f

#define NCHUNK_ 8
#define CHT_    256     // data timesteps per chunk
#define WARM_   96      // warmup timesteps (3 sub-chunks of 32)

typedef short bf16x8 __attribute__((ext_vector_type(8)));
typedef float f32x16 __attribute__((ext_vector_type(16)));

__device__ __forceinline__ float mulrn(float a, float b) { return __fmul_rn(a, b); }
__device__ __forceinline__ float addrn(float a, float b) { return __fadd_rn(a, b); }

__device__ __forceinline__ uint16_t f2bf(float x) {  // RNE f32->bf16
  uint32_t u = __float_as_uint(x);
  return (uint16_t)((u + 0x7FFFu + ((u >> 16) & 1u)) >> 16);
}

// nibble LUT (16 x uint2 in LDS, bank-conflict-free): bit j -> bf16 1.0/0.0
__device__ __forceinline__ bf16x8 expand8(const uint2* __restrict__ lut, uint32_t byt) {
  uint2 lo = lut[byt & 15u];
  uint2 h  = lut[byt >> 4];
  union { uint32_t w[4]; bf16x8 f; } r;
  r.w[0] = lo.x; r.w[1] = lo.y; r.w[2] = h.x; r.w[3] = h.y;
  return r.f;
}

__device__ __forceinline__ void lut_init(uint2* s_lut, int tid) {
  if (tid < 16) {
    uint32_t w0 = ((tid & 1) ? 0x3F80u : 0u) | ((tid & 2) ? 0x3F800000u : 0u);
    uint32_t w1 = ((tid & 4) ? 0x3F80u : 0u) | ((tid & 8) ? 0x3F800000u : 0u);
    s_lut[tid] = make_uint2(w0, w1);
  }
}

// ---------------------------------------------------------------------------
// prep (1024 threads): weight_norm (x64 folded). w1swz / wswz in the
// R5-R8-verified MFMA B-fragment swizzle. w3T[c][0..4]=w3, [5]=f2,[6]=1-f2.
// efo: e=floor(d)+1 (includes delay_shift1's +1). Zero counts.
// ---------------------------------------------------------------------------
__global__ __launch_bounds__(1024) void prep_kernel(
    const float* __restrict__ fc1_v, const float* __restrict__ fc1_g,
    const float* __restrict__ fc2_v, const float* __restrict__ fc2_g,
    const float* __restrict__ fc3_v, const float* __restrict__ fc3_g,
    const float* __restrict__ delay1, const float* __restrict__ delay2,
    uint16_t* __restrict__ w1swz, uint16_t* __restrict__ wswz,
    float* __restrict__ w3T, float4* __restrict__ efo1, float4* __restrict__ efo2,
    float* __restrict__ counts) {
  __shared__ float s_g2[NH_], s_n2[NH_];
  int tid = threadIdx.x;
  if (tid < NH_) {
    {
      float ss = 0.f;
      for (int c = 0; c < NH_; c++) { float vv = fc2_v[tid * NH_ + c]; ss = __fmaf_rn(vv, vv, ss); }
      s_n2[tid] = sqrtf(ss);
      s_g2[tid] = fc2_g[tid];
    }
    {
      float ss = 0.f;
      for (int c = 0; c < NIN_; c++) { float vv = fc1_v[tid * NIN_ + c]; ss = __fmaf_rn(vv, vv, ss); }
      float nrm = sqrtf(ss);
      float g = fc1_g[tid];
      int mt = tid >> 5;
      for (int c = 0; c < NIN_; c++) {
        float wv = 64.0f * __fdiv_rn(mulrn(g, fc1_v[tid * NIN_ + c]), nrm);
        int lane = (tid & 31) + 32 * ((c >> 3) & 1);
        int j = c & 7;
        w1swz[(mt * 64 + lane) * 8 + j] = f2bf(wv);
      }
    }
    {
      float d1 = delay1[tid];
      float fl = floorf(d1);
      float f = __fsub_rn(d1, fl);
      efo1[tid] = make_float4(__int_as_float((int)fl + 1), f, __fsub_rn(1.0f, f), 0.f);
      float d2 = delay2[tid];
      float fl2 = floorf(d2);
      float f2v = __fsub_rn(d2, fl2);
      efo2[tid] = make_float4(__int_as_float((int)fl2 + 1), f2v, __fsub_rn(1.0f, f2v), 0.f);
      w3T[tid * 8 + 5] = f2v;
      w3T[tid * 8 + 6] = __fsub_rn(1.0f, f2v);
      w3T[tid * 8 + 7] = 0.f;
    }
  }
  if (tid < NOUT_) {
    float ss = 0.f;
    for (int c = 0; c < NH_; c++) { float vv = fc3_v[tid * NH_ + c]; ss = __fmaf_rn(vv, vv, ss); }
    float nrm = sqrtf(ss);
    float g = fc3_g[tid];
    for (int c = 0; c < NH_; c++)
      w3T[c * 8 + tid] = 64.0f * __fdiv_rn(mulrn(g, fc3_v[tid * NH_ + c]), nrm);
  }
  if (tid < 3) counts[tid] = 0.f;
  __syncthreads();
  for (int i = tid; i < NH_ * NH_; i += 1024) {
    int o = i >> 7, c = i & 127;
    float wv = 64.0f * __fdiv_rn(mulrn(s_g2[o], fc2_v[i]), s_n2[o]);
    float d1 = delay1[c];
    float f = __fsub_rn(d1, floorf(d1));
    int lane = (o & 31) + 32 * ((c >> 3) & 1);
    int ks = c >> 4, j = c & 7, mt = o >> 5;
    wswz[((size_t)((0 * 4 + mt) * 8 + ks) * 64 + lane) * 8 + j] = f2bf(__fmul_rn(wv, f));
    wswz[((size_t)((1 * 4 + mt) * 8 + ks) * 64 + lane) * 8 + j] =
        f2bf(__fmul_rn(wv, __fsub_rn(1.0f, f)));
  }
}

// ---------------------------------------------------------------------------
// pack: input f32 spikes (B,16,T) -> 16-bit channel masks Xb[b][t] via ballot.
// ---------------------------------------------------------------------------
__global__ __launch_bounds__(256) void pack_kernel(const float* __restrict__ spike,
                                                   uint16_t* __restrict__ Xb) {
  int gw = blockIdx.x * 4 + (threadIdx.x >> 6);
  int lane = threadIdx.x & 63;
  int b = gw >> 5;
  int t = (gw & 31) * 64 + lane;
  const float* sp = spike + (size_t)b * NIN_ * T_ + t;
  uint32_t mask = 0;
#pragma unroll
  for (int c = 0; c < NIN_; c++) {
    unsigned long long bal = __ballot(sp[(size_t)c * T_] != 0.f);
    mask |= (uint32_t)((bal >> lane) & 1ull) << c;
  }
  Xb[(size_t)b * T_ + t] = (uint16_t)mask;
}

// ---------------------------------------------------------------------------
// Gather a wave's 2-tile (tiles A,B; 64o x 32t) MFMA result so that every
// lane holds all 32 t for one o, via 16 batched shfl_xor(32) (NOT in the
// scan chain). D layout (R6-R8-verified): row t = (r&3)+8*(r>>2)+4*hi,
// col o = lane&31. Then scan 32 steps fully in-register; o = pair*64+lane.
// ---------------------------------------------------------------------------
#define GATHER_AND_SCAN(aA, aB, hi, u, v, m)                               \
  {                                                                        \
    float evenQ[16], oddQ[16];                                             \
    _Pragma("unroll") for (int r = 0; r < 16; r++) {                       \
      float tmp = hi ? aA[r] : aB[r];                                      \
      float rcv = __shfl_xor(tmp, 32, 64);                                 \
      evenQ[r] = hi ? rcv : aA[r];                                         \
      oddQ[r] = hi ? aB[r] : rcv;                                          \
    }                                                                      \
    m = 0u;                                                                \
    _Pragma("unroll") for (int t = 0; t < 32; t++) {                       \
      int q = t >> 2;                                                      \
      int base = 4 * (q >> 1) + (t & 3);                                   \
      float z = (q & 1) ? oddQ[base] : evenQ[base];                        \
      u = addrn(mulrn(ALPHA_I_, u), z);                                    \
      v = addrn(mulrn(ALPHA_V_, v), u);                                    \
      bool sbit = (v >= THETA_);                                           \
      v = sbit ? 0.f : v;                                                  \
      m |= sbit ? (1u << t) : 0u;                                          \
    }                                                                      \
  }

// ---------------------------------------------------------------------------
// Fused layer 1: wave = 2 o-tiles (shared A-frag from input bits, 2 MFMA),
// gather + in-register scan, coalesced bit store + counts. Waves independent.
// grid (NCHUNK_, B), block 128 (2 waves = o pairs {0-63},{64-127}).
// ---------------------------------------------------------------------------
__global__ __launch_bounds__(128, 2) void fused_layer1(const uint16_t* __restrict__ Xb,
                                                       const uint16_t* __restrict__ w1swz,
                                                       uint32_t* __restrict__ sbits2,
                                                       float* __restrict__ cnt) {
  __shared__ uint2 s_lut[16];
  int tid = threadIdx.x;
  int pair = tid >> 6, lane = tid & 63;
  int hi = lane >> 5, tl = lane & 31;
  int ci = blockIdx.x, b = blockIdx.y;
  lut_init(s_lut, tid);
  const bf16x8* w1v = (const bf16x8*)w1swz;
  bf16x8 wA = w1v[(pair * 2 + 0) * 64 + lane];
  bf16x8 wB = w1v[(pair * 2 + 1) * 64 + lane];
  __syncthreads();

  int wch = (ci == 0) ? 0 : (WARM_ / 32);
  int nch = CHT_ / 32 + wch;
  int chbase0 = ci * CHT_ - wch * 32;
  const uint16_t* xb = Xb + (size_t)b * T_;
  uint32_t* sb = sbits2 + (size_t)b * 68 * NH_;

  float u = 0.f, v = 0.f, csum = 0.f;
  uint32_t x = xb[chbase0 + tl];
  for (int g = 0; g < nch; g++) {
    uint32_t xn = (g + 1 < nch) ? (uint32_t)xb[chbase0 + (g + 1) * 32 + tl] : 0u;
    uint32_t byt = (x >> (8 * hi)) & 0xFFu;
    bf16x8 e = expand8(s_lut, byt);
    f32x16 aA, aB;
#pragma unroll
    for (int r = 0; r < 16; r++) { aA[r] = 0.f; aB[r] = 0.f; }
    aA = __builtin_amdgcn_mfma_f32_32x32x16_bf16(e, wA, aA, 0, 0, 0);
    aB = __builtin_amdgcn_mfma_f32_32x32x16_bf16(e, wB, aB, 0, 0, 0);
    uint32_t m;
    GATHER_AND_SCAN(aA, aB, hi, u, v, m);
    if (g >= wch) {
      int gw = (chbase0 + g * 32) >> 5;
      sb[(2 + gw) * NH_ + pair * 64 + lane] = m;
      int pc = __popc(m);
      if (gw == 63) pc -= (int)(m >> 31);
      csum += (float)pc;
    }
    x = xn;
  }
  if (ci == 0) { sb[0 * NH_ + pair * 64 + lane] = 0u; sb[1 * NH_ + pair * 64 + lane] = 0u; }
  if (ci == NCHUNK_ - 1) { sb[66 * NH_ + pair * 64 + lane] = 0u; sb[67 * NH_ + pair * 64 + lane] = 0u; }
  for (int off = 32; off; off >>= 1) csum += __shfl_down(csum, off, 64);
  if (lane == 0) atomicAdd(cnt, csum);
}

// ---------------------------------------------------------------------------
// Fused layer 2: block = 2 waves of the SAME o-pair (pb), handling chunks
// 2*bx and 2*bx+1. Weight fragments staged ONCE into LDS (32 KB) -- fixes
// the R8 register-spill/global-reload (VGPR_Count 108 < 128-reg footprint).
// Per ks: 4 ds_read_b128 weights + 2 LUT expands + 4 MFMA. Barrier-free loop.
// grid (NCHUNK_/2, 2, B), block 128.
// ---------------------------------------------------------------------------
__global__ __launch_bounds__(128) void fused_layer2(const uint32_t* __restrict__ PTpad,
                                                    const uint16_t* __restrict__ wswz,
                                                    uint32_t* __restrict__ sbits2,
                                                    float* __restrict__ cnt) {
  __shared__ uint16_t s_w[4 * 8 * 64 * 8];  // [arr][ks][lane][j], 32 KB
  __shared__ uint2 s_lut[16];
  int tid = threadIdx.x;
  int wv = tid >> 6, lane = tid & 63;
  int hi = lane >> 5, tl = lane & 31;
  int pb = blockIdx.y, b = blockIdx.z;
  int ci = blockIdx.x * 2 + wv;
  lut_init(s_lut, tid);
  {
    // arr: 0=WfA 1=WofA 2=WfB 3=WofB  (A: mt=2pb, B: mt=2pb+1)
    const uint4* wsrc = (const uint4*)wswz;
    uint4* wdst = (uint4*)s_w;
    for (int i = tid; i < 2048; i += 128) {
      int arr = i >> 9, rest = i & 511;      // rest = ks*64 + lane
      int half = arr & 1, mt = 2 * pb + (arr >> 1);
      wdst[i] = wsrc[(size_t)((half * 4 + mt) * 8) * 64 + rest];
    }
  }
  __syncthreads();

  int wch = (ci == 0) ? 0 : (WARM_ / 32);
  int nch = CHT_ / 32 + wch;
  int chbase0 = ci * CHT_ - wch * 32;
  const uint4* pt = (const uint4*)PTpad + (size_t)b * (T_ + 1);
  uint32_t* sb = sbits2 + (size_t)b * 68 * NH_;
  const bf16x8* wlds = (const bf16x8*)s_w;

  float u = 0.f, v = 0.f, csum = 0.f;
  uint4 R0 = pt[chbase0 + tl];
  uint4 R1 = pt[chbase0 + tl + 1];
  for (int g = 0; g < nch; g++) {
    uint4 R0n = R0, R1n = R1;
    if (g + 1 < nch) {
      R0n = pt[chbase0 + (g + 1) * 32 + tl];
      R1n = pt[chbase0 + (g + 1) * 32 + tl + 1];
    }
    uint32_t r0w[4] = {R0.x, R0.y, R0.z, R0.w};
    uint32_t r1w[4] = {R1.x, R1.y, R1.z, R1.w};
    f32x16 aA, aB;
#pragma unroll
    for (int r = 0; r < 16; r++) { aA[r] = 0.f; aB[r] = 0.f; }
#pragma unroll
    for (int ks = 0; ks < 8; ks++) {
      int sh = 16 * (ks & 1) + 8 * hi;
      uint32_t b0 = (r0w[ks >> 1] >> sh) & 0xFFu;  // tap s[t-e-1] -> Wf
      uint32_t b1 = (r1w[ks >> 1] >> sh) & 0xFFu;  // tap s[t-e]   -> Wof
      bf16x8 e0 = expand8(s_lut, b0);
      bf16x8 e1 = expand8(s_lut, b1);
      bf16x8 wfA = wlds[0 * 512 + ks * 64 + lane];
      bf16x8 woA = wlds[1 * 512 + ks * 64 + lane];
      bf16x8 wfB = wlds[2 * 512 + ks * 64 + lane];
      bf16x8 woB = wlds[3 * 512 + ks * 64 + lane];
      aA = __builtin_amdgcn_mfma_f32_32x32x16_bf16(e0, wfA, aA, 0, 0, 0);
      aA = __builtin_amdgcn_mfma_f32_32x32x16_bf16(e1, woA, aA, 0, 0, 0);
      aB = __builtin_amdgcn_mfma_f32_32x32x16_bf16(e0, wfB, aB, 0, 0, 0);
      aB = __builtin_amdgcn_mfma_f32_32x32x16_bf16(e1, woB, aB, 0, 0, 0);
    }
    uint32_t m;
    GATHER_AND_SCAN(aA, aB, hi, u, v, m);
    if (g >= wch) {
      int gw = (chbase0 + g * 32) >> 5;
      sb[(2 + gw) * NH_ + pb * 64 + lane] = m;
      int pc = __popc(m);
      if (gw == 63) pc -= (int)(m >> 31);
      csum += (float)pc;
    }
    R0 = R0n; R1 = R1n;
  }
  if (ci == 0) { sb[0 * NH_ + pb * 64 + lane] = 0u; sb[1 * NH_ + pb * 64 + lane] = 0u; }
  if (ci == NCHUNK_ - 1) { sb[66 * NH_ + pb * 64 + lane] = 0u; sb[67 * NH_ + pb * 64 + lane] = 0u; }
  for (int off = 32; off; off >>= 1) csum += __shfl_down(csum, off, 64);
  if (lane == 0) atomicAdd(cnt, csum);
}

// ---------------------------------------------------------------------------
// bit transpose + delay pre-shift, PARALLELIZED: grid (T/256, B); each block
// covers 256 t's of one b; one t per thread. 10-word LDS window per channel.
// PTpad[b][1+t] bit c = s[c][t - e_c]; PTpad[b][0] = 0.
// ---------------------------------------------------------------------------
__global__ __launch_bounds__(256) void transpose_kernel(const uint32_t* __restrict__ sbits2,
                                                        const float4* __restrict__ efo,
                                                        uint32_t* __restrict__ PTpad) {
  __shared__ uint32_t rows[NH_][11];  // k=0..9 (+1 pad)
  int tid = threadIdx.x;
  int b = blockIdx.y;
  int t0blk = blockIdx.x * 256;
  int w0 = t0blk >> 5;
  const uint32_t* src = sbits2 + (size_t)b * 68 * NH_;
  for (int i = tid; i < NH_ * 10; i += 256) {
    int k = i >> 7, c = i & 127;
    rows[c][k] = src[(1 + w0 + k) * NH_ + c];  // slot 1+w0+k (guards at 0,1,66,67)
  }
  __syncthreads();

  int t = t0blk + tid;
  uint32_t wacc[4] = {0u, 0u, 0u, 0u};
#pragma unroll
  for (int c = 0; c < NH_; c++) {
    int e = __float_as_int(efo[c].x);           // uniform -> scalar load
    int bitpos = t - e;                          // >= t0blk-11
    int wi = (bitpos >> 5) - w0 + 1;             // in [0, 9]
    int sh = bitpos & 31;
    uint32_t lo = rows[c][wi];
    uint32_t hi2 = rows[c][wi + 1];
    uint32_t bit = (uint32_t)(((((unsigned long long)hi2 << 32) | lo) >> sh)) & 1u;
    wacc[c >> 5] |= bit << (c & 31);
  }
  uint4* outp = (uint4*)PTpad + (size_t)b * (T_ + 1);
  outp[1 + t] = make_uint4(wacc[0], wacc[1], wacc[2], wacc[3]);
  if (t == 0) outp[0] = make_uint4(0u, 0u, 0u, 0u);
}

// ---------------------------------------------------------------------------
// gemm3 (vector): 5 outputs from pre-shifted PT rows.
// ---------------------------------------------------------------------------
__global__ __launch_bounds__(256) void gemm3_kernel(const uint32_t* __restrict__ PTpad,
                                                    const float* __restrict__ w3T,
                                                    float* __restrict__ z) {
  int tid = threadIdx.x;
  int t = blockIdx.x * 256 + tid;
  int b = blockIdx.y;
  const uint4* pt = (const uint4*)PTpad + (size_t)b * (T_ + 1);
  uint4 R0 = pt[t];
  uint4 R1 = pt[t + 1];
  uint32_t r0w[4] = {R0.x, R0.y, R0.z, R0.w};
  uint32_t r1w[4] = {R1.x, R1.y, R1.z, R1.w};

  float acc[NOUT_];
#pragma unroll
  for (int o = 0; o < NOUT_; o++) acc[o] = 0.f;

#pragma unroll
  for (int c = 0; c < NH_; c++) {
    const float* wc = w3T + (c << 3);
    float f = wc[5], omf = wc[6];
    float fb0 = (float)((r0w[c >> 5] >> (c & 31)) & 1u);
    float fb1 = (float)((r1w[c >> 5] >> (c & 31)) & 1u);
    float val = __fmaf_rn(omf, fb1, __fmul_rn(f, fb0));
#pragma unroll
    for (int o = 0; o < NOUT_; o++) acc[o] = __fmaf_rn(wc[o], val, acc[o]);
  }

#pragma unroll
  for (int o = 0; o < NOUT_; o++)
    z[((size_t)b * NOUT_ + o) * T_ + t] = acc[o];
}

// ---------------------------------------------------------------------------
// Chunked layer-3 scan: thread per (chunk, b, o); 96-step warmup; f32 SHIFTED
// output (out[t]=s[t-1]) via float4 stores; count excludes t=T-1.
// ---------------------------------------------------------------------------
__global__ __launch_bounds__(256) void scan3_kernel(const float* __restrict__ z3,
                                                    float* __restrict__ out,
                                                    float* __restrict__ cnt) {
  int id = blockIdx.x * 256 + threadIdx.x;
  int row = id % (B_ * NOUT_);
  int ci = id / (B_ * NOUT_);
  int tstart = ci * CHT_;
  int t0 = (ci == 0) ? 0 : tstart - WARM_;
  const float4* zp4 = (const float4*)(z3 + (size_t)row * T_);

  float u = 0.f, v = 0.f, carry = 0.f;
  int cnt_i = 0;
  for (int gg = t0 / 16; gg < tstart / 16; gg++) {
#pragma unroll
    for (int q = 0; q < 4; q++) {
      float4 cv = zp4[gg * 4 + q];
      float zv[4] = {cv.x, cv.y, cv.z, cv.w};
#pragma unroll
      for (int j = 0; j < 4; j++) {
        u = addrn(mulrn(ALPHA_I_, u), zv[j]);
        v = addrn(mulrn(ALPHA_V_, v), u);
        bool s = (v >= THETA_);
        v = s ? 0.f : v;
        carry = s ? 1.f : 0.f;
      }
    }
  }
  float4* op4 = (float4*)(out + (size_t)row * T_ + tstart);
  for (int gg = 0; gg < CHT_ / 16; gg++) {
    float sarr[16];
#pragma unroll
    for (int q = 0; q < 4; q++) {
      float4 cv = zp4[(tstart / 16 + gg) * 4 + q];
      float zv[4] = {cv.x, cv.y, cv.z, cv.w};
#pragma unroll
      for (int j = 0; j < 4; j++) {
        u = addrn(mulrn(ALPHA_I_, u), zv[j]);
        v = addrn(mulrn(ALPHA_V_, v), u);
        bool s = (v >= THETA_);
        v = s ? 0.f : v;
        sarr[q * 4 + j] = s ? 1.f : 0.f;
      }
    }
#pragma unroll
    for (int k = 0; k < 16; k++) {
      int t = tstart + gg * 16 + k;
      if (t < T_ - 1) cnt_i += (sarr[k] != 0.f) ? 1 : 0;
    }
    op4[gg * 4 + 0] = make_float4(carry, sarr[0], sarr[1], sarr[2]);
    op4[gg * 4 + 1] = make_float4(sarr[3], sarr[4], sarr[5], sarr[6]);
    op4[gg * 4 + 2] = make_float4(sarr[7], sarr[8], sarr[9], sarr[10]);
    op4[gg * 4 + 3] = make_float4(sarr[11], sarr[12], sarr[13], sarr[14]);
    carry = sarr[15];
  }
  float c = (float)cnt_i;
  for (int off = 32; off; off >>= 1) c += __shfl_down(c, off, 64);
  if ((threadIdx.x & 63) == 0) atomicAdd(cnt, c);
}

// ---------------------------------------------------------------------------
extern "C" void kernel_launch(void* const* d_in, const int* in_sizes, int n_in,
                              void* d_out, int out_size, void* d_ws, size_t ws_size,
                              hipStream_t stream) {
  (void)in_sizes; (void)n_in; (void)out_size; (void)ws_size;
  const float* spike  = (const float*)d_in[0];
  const float* fc1_v  = (const float*)d_in[1];
  const float* fc1_g  = (const float*)d_in[2];
  const float* fc2_v  = (const float*)d_in[3];
  const float* fc2_g  = (const float*)d_in[4];
  const float* fc3_v  = (const float*)d_in[5];
  const float* fc3_g  = (const float*)d_in[6];
  const float* delay1 = (const float*)d_in[7];
  const float* delay2 = (const float*)d_in[8];
  float* out = (float*)d_out;

  float* ws = (float*)d_ws;
  float* w3T       = ws;                         // 1024 f
  float4* efo1     = (float4*)(ws + 1024);       // 512 f
  float4* efo2     = (float4*)(ws + 1536);       // 512 f
  uint16_t* w1swz  = (uint16_t*)(ws + 2048);     // 2048 u16 = 1024 f
  uint16_t* wswz   = (uint16_t*)(ws + 3072);     // 32768 u16 = 16384 f
  uint16_t* Xb     = (uint16_t*)(ws + 19456);    // B*T u16 = 131072 f
  uint32_t* sbits2 = (uint32_t*)(ws + 150528);   // B*68*128 u32
  uint32_t* PTpad  = (uint32_t*)(ws + 1264640);  // B*(T+1)*4 u32, 16B-aligned
  float* z3        = ws + 2313728;               // B*5*T f32
  float* counts = out + (size_t)B_ * NOUT_ * T_;

  prep_kernel<<<1, 1024, 0, stream>>>(fc1_v, fc1_g, fc2_v, fc2_g, fc3_v, fc3_g,
                                      delay1, delay2, w1swz, wswz, w3T, efo1, efo2, counts);

  pack_kernel<<<dim3(B_ * T_ / 64 / 4), 256, 0, stream>>>(spike, Xb);

  fused_layer1<<<dim3(NCHUNK_, B_), 128, 0, stream>>>(Xb, w1swz, sbits2, counts + 0);
  transpose_kernel<<<dim3(T_ / 256, B_), 256, 0, stream>>>(sbits2, efo1, PTpad);

  fused_layer2<<<dim3(NCHUNK_ / 2, 2, B_), 128, 0, stream>>>(PTpad, wswz, sbits2, counts + 1);
  transpose_kernel<<<dim3(T_ / 256, B_), 256, 0, stream>>>(sbits2, efo2, PTpad);

  gemm3_kernel<<<dim3(T_ / 256, B_), 256, 0, stream>>>(PTpad, w3T, z3);
  scan3_kernel<<<dim3(NCHUNK_ * B_ * NOUT_ / 256), 256, 0, stream>>>(z3, out, counts + 2);
}